// Round 11
// baseline (570.979 us; speedup 1.0000x reference)
//
#include <hip/hip_runtime.h>
#include <math.h>

typedef unsigned short u16;
typedef __attribute__((ext_vector_type(8))) short short8;
typedef __attribute__((ext_vector_type(4))) float f32x4;

#define T_TOK 2048
#define H_DIM 2048
#define E_NUM 16
#define F_DIM 1024
#define EFD   16384
#define M_DIM 512
#define SLOTMAX 2048

__device__ __forceinline__ u16 f2bf(float x) {
  union { float f; unsigned u; } c; c.f = x;
  unsigned r = c.u + 0x7FFFu + ((c.u >> 16) & 1u);   // RNE
  return (u16)(r >> 16);
}
__device__ __forceinline__ float bf2f(u16 h) {
  union { unsigned u; float f; } c; c.u = ((unsigned)h) << 16;
  return c.f;
}
__device__ __forceinline__ void gl_lds16(const void* g, void* l) {
  __builtin_amdgcn_global_load_lds((const __attribute__((address_space(1))) void*)g,
                                   (__attribute__((address_space(3))) void*)l, 16, 0, 0);
}

// ---------------- conversion kernels ----------------
__global__ void k_cvt(const float* __restrict__ s, u16* __restrict__ d, int n8) {
  int i = blockIdx.x * 256 + threadIdx.x;
  if (i >= n8) return;
  const float4* sp = (const float4*)(s + (size_t)i * 8);
  float4 a = sp[0], b = sp[1];
  union { short8 v; u16 e[8]; } o;
  o.e[0] = f2bf(a.x); o.e[1] = f2bf(a.y); o.e[2] = f2bf(a.z); o.e[3] = f2bf(a.w);
  o.e[4] = f2bf(b.x); o.e[5] = f2bf(b.y); o.e[6] = f2bf(b.z); o.e[7] = f2bf(b.w);
  *(short8*)(d + (size_t)i * 8) = o.v;
}

// one launch: Wg, Wu, Wd fp32 -> bf16 (16384 blocks each)
__global__ void k_cvt3(const float* __restrict__ a, const float* __restrict__ b,
                       const float* __restrict__ c, u16* __restrict__ da,
                       u16* __restrict__ db, u16* __restrict__ dc) {
  int blk = blockIdx.x;
  const float* s; u16* d; int base;
  if (blk < 16384)      { s = a; d = da; base = blk; }
  else if (blk < 32768) { s = b; d = db; base = blk - 16384; }
  else                  { s = c; d = dc; base = blk - 32768; }
  int i = base * 256 + threadIdx.x;
  const float4* sp = (const float4*)(s + (size_t)i * 8);
  float4 va = sp[0], vb = sp[1];
  union { short8 v; u16 e[8]; } o;
  o.e[0] = f2bf(va.x); o.e[1] = f2bf(va.y); o.e[2] = f2bf(va.z); o.e[3] = f2bf(va.w);
  o.e[4] = f2bf(vb.x); o.e[5] = f2bf(vb.y); o.e[6] = f2bf(vb.z); o.e[7] = f2bf(vb.w);
  *(short8*)(d + (size_t)i * 8) = o.v;
}

// Wd[e,h,f] -> Wdp[h, e*F+f] (bf16)  [fallback path only]
__global__ void k_cvt_wd(const float* __restrict__ wd, u16* __restrict__ wdp) {
  int i = blockIdx.x * 256 + threadIdx.x;
  if (i >= (E_NUM * H_DIM * F_DIM) / 8) return;
  int f8 = i & 127;
  int h  = (i >> 7) & (H_DIM - 1);
  int e  = i >> 18;
  const float4* sp = (const float4*)(wd + (size_t)(e * H_DIM + h) * F_DIM + f8 * 8);
  float4 a = sp[0], b = sp[1];
  union { short8 v; u16 ee[8]; } o;
  o.ee[0] = f2bf(a.x); o.ee[1] = f2bf(a.y); o.ee[2] = f2bf(a.z); o.ee[3] = f2bf(a.w);
  o.ee[4] = f2bf(b.x); o.ee[5] = f2bf(b.y); o.ee[6] = f2bf(b.z); o.ee[7] = f2bf(b.w);
  *(short8*)(wdp + (size_t)h * EFD + e * F_DIM + f8 * 8) = o.v;
}

// ============ shared 8-phase machinery (identical schedule to R4/R6, verified) ============
#define STAGE8(s_, ab_, h_, t_) do {                                       \
    const u16* s0_ = srcp[ab_][h_][0] + (size_t)(t_) * 64;                 \
    const u16* s1_ = srcp[ab_][h_][1] + (size_t)(t_) * 64;                 \
    u16* d_ = lds + (((s_) * 2 + (ab_)) * 16384 + (h_) * 8192 + tid * 8);  \
    gl_lds16(s0_, d_); gl_lds16(s1_, d_ + 4096);                           \
  } while (0)

// ---------------- merged gate+up: actC[e][slot][f] = w*silu(g)*u ----------------
#define PHASE_GU(p_, STAGE_STMT, WAIT_STMT)                                       \
  {                                                                               \
    afr[0][0] = *(const short8*)(LA + (abase + (2*(p_)) * 1024));                 \
    afr[0][1] = *(const short8*)(LA + ((abase + (2*(p_)) * 1024) ^ 32));          \
    afr[1][0] = *(const short8*)(LA + (abase + (2*(p_)+1) * 1024));               \
    afr[1][1] = *(const short8*)(LA + ((abase + (2*(p_)+1) * 1024) ^ 32));        \
    if ((p_) == 0) {                                                              \
      _Pragma("unroll") for (int n = 0; n < 2; ++n) {                             \
        gfr[n][0] = *(const short8*)(LB + (bbase + n * 1024));                    \
        gfr[n][1] = *(const short8*)(LB + ((bbase + n * 1024) ^ 32));             \
        ufr[n][0] = *(const short8*)(LB + (8192 + bbase + n * 1024));             \
        ufr[n][1] = *(const short8*)(LB + ((8192 + bbase + n * 1024) ^ 32));      \
      }                                                                           \
    }                                                                             \
    STAGE_STMT; WAIT_STMT;                                                        \
    __builtin_amdgcn_s_barrier();                                                 \
    __builtin_amdgcn_s_setprio(1);                                                \
    _Pragma("unroll") for (int n = 0; n < 2; ++n)                                 \
      _Pragma("unroll") for (int kk = 0; kk < 2; ++kk) {                          \
        accg[2*(p_)][n]   = __builtin_amdgcn_mfma_f32_16x16x32_bf16(afr[0][kk], gfr[n][kk], accg[2*(p_)][n],   0,0,0); \
        accg[2*(p_)+1][n] = __builtin_amdgcn_mfma_f32_16x16x32_bf16(afr[1][kk], gfr[n][kk], accg[2*(p_)+1][n], 0,0,0); \
        accu[2*(p_)][n]   = __builtin_amdgcn_mfma_f32_16x16x32_bf16(afr[0][kk], ufr[n][kk], accu[2*(p_)][n],   0,0,0); \
        accu[2*(p_)+1][n] = __builtin_amdgcn_mfma_f32_16x16x32_bf16(afr[1][kk], ufr[n][kk], accu[2*(p_)+1][n], 0,0,0); \
      }                                                                           \
    __builtin_amdgcn_s_setprio(0);                                                \
    __builtin_amdgcn_s_barrier();                                                 \
  }

__global__ __launch_bounds__(512, 2)
void k8gu(const u16* __restrict__ Xbf, const u16* __restrict__ Wg, const u16* __restrict__ Wu,
          const int* __restrict__ list, const float* __restrict__ wlist,
          const int* __restrict__ counts, u16* __restrict__ actC)
{
  extern __shared__ u16 lds[];
  const int tid = threadIdx.x;
  const int wid = tid >> 6, lane = tid & 63;
  const int wm = wid >> 2, wn = wid & 3;       // wave tile: 128 slots x 32 cols
  const int lr = lane & 15, lk = lane >> 4;
  const int e = blockIdx.z;
  const int cnt = counts[e];
  const int bn0 = blockIdx.x * 128;
  const int nt = H_DIM / 64;
  const int rl  = tid >> 3;
  const int csw = ((tid & 7) ^ (rl & 7)) * 8;
  const int abase = (wm * 128 + lr) * 64 + (lk ^ (lr & 7)) * 8;
  const int bbase = (wn * 32 + lr) * 64 + (lk ^ (lr & 7)) * 8;

  for (int rep = 0; rep < 2; ++rep) {
    const int bm0 = blockIdx.y * 512 + rep * 256;
    if (bm0 >= cnt) break;

    const u16* srcp[2][2][2];
#pragma unroll
    for (int h = 0; h < 2; ++h)
#pragma unroll
      for (int c = 0; c < 2; ++c) {
        int ar = list[e * T_TOK + bm0 + h * 128 + c * 64 + rl];
        srcp[0][h][c] = Xbf + (size_t)ar * H_DIM + csw;
        size_t brow = (size_t)(e * F_DIM + bn0 + c * 64 + rl);
        srcp[1][h][c] = (h == 0 ? Wg : Wu) + brow * H_DIM + csw;
      }

    f32x4 accg[8][2], accu[8][2];
    f32x4 zero4 = {0.f, 0.f, 0.f, 0.f};
#pragma unroll
    for (int m = 0; m < 8; ++m)
#pragma unroll
      for (int n = 0; n < 2; ++n) { accg[m][n] = zero4; accu[m][n] = zero4; }

    STAGE8(0, 0, 0, 0); STAGE8(0, 0, 1, 0); STAGE8(0, 1, 0, 0); STAGE8(0, 1, 1, 0);
    STAGE8(1, 1, 0, 1); STAGE8(1, 1, 1, 1);
    asm volatile("s_waitcnt vmcnt(4)" ::: "memory");
    __builtin_amdgcn_s_barrier();

    short8 afr[2][2], gfr[2][2], ufr[2][2];
    for (int t = 0; t < nt; ++t) {
      const int s = t & 1;
      const u16* LA = lds + (size_t)(s * 2) * 16384;
      const u16* LB = lds + (size_t)(s * 2 + 1) * 16384;
      PHASE_GU(0, if (t + 1 < nt) STAGE8(s ^ 1, 0, 0, t + 1), ((void)0));
      PHASE_GU(1, if (t + 1 < nt) STAGE8(s ^ 1, 0, 1, t + 1), ((void)0));
      PHASE_GU(2, if (t + 2 < nt) STAGE8(s, 1, 0, t + 2), ((void)0));
      PHASE_GU(3, if (t + 2 < nt) STAGE8(s, 1, 1, t + 2),
               if (t + 2 < nt) { asm volatile("s_waitcnt vmcnt(4)" ::: "memory"); }
               else            { asm volatile("s_waitcnt vmcnt(0)" ::: "memory"); });
      __builtin_amdgcn_sched_barrier(0);
    }

#pragma unroll
    for (int m = 0; m < 8; ++m)
#pragma unroll
      for (int i = 0; i < 4; ++i) {
        int slot = bm0 + wm * 128 + m * 16 + lk * 4 + i;
        float w = wlist[e * T_TOK + slot];
#pragma unroll
        for (int n = 0; n < 2; ++n) {
          int col = bn0 + wn * 32 + n * 16 + lr;
          float g = accg[m][n][i], u = accu[m][n][i];
          float act = w * (g / (1.f + expf(-g))) * u;
          actC[((size_t)e * SLOTMAX + slot) * F_DIM + col] = f2bf(act);
        }
      }
  }
}

// ---------------- per-expert down: outE[e][slot][h] = actC_e @ Wd_e^T (bf16) ------------
#define PHASE_D(p_, STAGE_STMT, WAIT_STMT)                                        \
  {                                                                               \
    afr[0][0] = *(const short8*)(LA + (abase + (2*(p_)) * 1024));                 \
    afr[0][1] = *(const short8*)(LA + ((abase + (2*(p_)) * 1024) ^ 32));          \
    afr[1][0] = *(const short8*)(LA + (abase + (2*(p_)+1) * 1024));               \
    afr[1][1] = *(const short8*)(LA + ((abase + (2*(p_)+1) * 1024) ^ 32));        \
    if ((p_) == 0) {                                                              \
      _Pragma("unroll") for (int n = 0; n < 4; ++n) {                             \
        bfr[n][0] = *(const short8*)(LB + (bbase + n * 1024));                    \
        bfr[n][1] = *(const short8*)(LB + ((bbase + n * 1024) ^ 32));             \
      }                                                                           \
    }                                                                             \
    STAGE_STMT; WAIT_STMT;                                                        \
    __builtin_amdgcn_s_barrier();                                                 \
    __builtin_amdgcn_s_setprio(1);                                                \
    _Pragma("unroll") for (int n = 0; n < 4; ++n) {                               \
      acc[2*(p_)][n]   = __builtin_amdgcn_mfma_f32_16x16x32_bf16(afr[0][0], bfr[n][0], acc[2*(p_)][n],   0,0,0); \
      acc[2*(p_)][n]   = __builtin_amdgcn_mfma_f32_16x16x32_bf16(afr[0][1], bfr[n][1], acc[2*(p_)][n],   0,0,0); \
      acc[2*(p_)+1][n] = __builtin_amdgcn_mfma_f32_16x16x32_bf16(afr[1][0], bfr[n][0], acc[2*(p_)+1][n], 0,0,0); \
      acc[2*(p_)+1][n] = __builtin_amdgcn_mfma_f32_16x16x32_bf16(afr[1][1], bfr[n][1], acc[2*(p_)+1][n], 0,0,0); \
    }                                                                             \
    __builtin_amdgcn_s_setprio(0);                                                \
    __builtin_amdgcn_s_barrier();                                                 \
  }

__global__ __launch_bounds__(512, 2)
void k8d(const u16* __restrict__ actC, const u16* __restrict__ Wd,
         const int* __restrict__ counts, u16* __restrict__ outE)
{
  extern __shared__ u16 lds[];
  const int tid = threadIdx.x;
  const int wid = tid >> 6, lane = tid & 63;
  const int wm = wid >> 2, wn = wid & 3;       // wave tile: 128 slots x 64 h
  const int lr = lane & 15, lk = lane >> 4;
  const int e = blockIdx.z;
  const int cnt = counts[e];
  const int bn0 = blockIdx.x * 256;
  const int nt = F_DIM / 64;
  const int rl  = tid >> 3;
  const int csw = ((tid & 7) ^ (rl & 7)) * 8;
  const int abase = (wm * 128 + lr) * 64 + (lk ^ (lr & 7)) * 8;
  const int bbase = (wn * 64 + lr) * 64 + (lk ^ (lr & 7)) * 8;

  for (int rep = 0; rep < 2; ++rep) {
    const int bm0 = blockIdx.y * 512 + rep * 256;
    if (bm0 >= cnt) break;

    const u16* srcp[2][2][2];
#pragma unroll
    for (int h = 0; h < 2; ++h)
#pragma unroll
      for (int c = 0; c < 2; ++c) {
        srcp[0][h][c] = actC + ((size_t)e * SLOTMAX + bm0 + h * 128 + c * 64 + rl) * F_DIM + csw;
        srcp[1][h][c] = Wd + (size_t)e * H_DIM * F_DIM
                      + (size_t)(bn0 + h * 128 + c * 64 + rl) * F_DIM + csw;
      }

    f32x4 acc[8][4];
    f32x4 zero4 = {0.f, 0.f, 0.f, 0.f};
#pragma unroll
    for (int m = 0; m < 8; ++m)
#pragma unroll
      for (int n = 0; n < 4; ++n) acc[m][n] = zero4;

    STAGE8(0, 0, 0, 0); STAGE8(0, 0, 1, 0); STAGE8(0, 1, 0, 0); STAGE8(0, 1, 1, 0);
    STAGE8(1, 1, 0, 1); STAGE8(1, 1, 1, 1);
    asm volatile("s_waitcnt vmcnt(4)" ::: "memory");
    __builtin_amdgcn_s_barrier();

    short8 afr[2][2], bfr[4][2];
    for (int t = 0; t < nt; ++t) {
      const int s = t & 1;
      const u16* LA = lds + (size_t)(s * 2) * 16384;
      const u16* LB = lds + (size_t)(s * 2 + 1) * 16384;
      PHASE_D(0, if (t + 1 < nt) STAGE8(s ^ 1, 0, 0, t + 1), ((void)0));
      PHASE_D(1, if (t + 1 < nt) STAGE8(s ^ 1, 0, 1, t + 1), ((void)0));
      PHASE_D(2, if (t + 2 < nt) STAGE8(s, 1, 0, t + 2), ((void)0));
      PHASE_D(3, if (t + 2 < nt) STAGE8(s, 1, 1, t + 2),
              if (t + 2 < nt) { asm volatile("s_waitcnt vmcnt(4)" ::: "memory"); }
              else            { asm volatile("s_waitcnt vmcnt(0)" ::: "memory"); });
      __builtin_amdgcn_sched_barrier(0);
    }

#pragma unroll
    for (int m = 0; m < 8; ++m)
#pragma unroll
      for (int n = 0; n < 4; ++n)
#pragma unroll
        for (int i = 0; i < 4; ++i) {
          int slot = bm0 + wm * 128 + m * 16 + lk * 4 + i;
          int col  = bn0 + wn * 64 + n * 16 + lr;
          outE[((size_t)e * SLOTMAX + slot) * H_DIM + col] = f2bf(acc[m][n][i]);
        }
  }
}

// ---------------- gather-reduce: y[t,h] = sum_{r<8} outE[tokmap[t][r]][h] ----------------
__global__ void k_gather(const u16* __restrict__ outE, const int* __restrict__ tokmap,
                         float* __restrict__ y)
{
  __shared__ int tm[8];
  const int t = blockIdx.x, tid = threadIdx.x;
  if (tid < 8) tm[tid] = tokmap[t * 8 + tid];
  __syncthreads();
  float s[8] = {0.f, 0.f, 0.f, 0.f, 0.f, 0.f, 0.f, 0.f};
#pragma unroll
  for (int r = 0; r < 8; ++r) {
    union { short8 v; u16 e[8]; } row;
    row.v = *(const short8*)(outE + (size_t)tm[r] * H_DIM + tid * 8);
#pragma unroll
    for (int j = 0; j < 8; ++j) s[j] += bf2f(row.e[j]);
  }
  float* dst = y + (size_t)t * H_DIM + tid * 8;
#pragma unroll
  for (int j = 0; j < 8; ++j) dst[j] = s[j];
}

// ---------------- small GEMM for h1: C = silu(A*B^T + bias) -> bf16 ----------------
__global__ __launch_bounds__(256, 2)
void k_gemm_h1(const u16* __restrict__ A, const u16* __restrict__ B, int Ndim, int Kdim,
               u16* __restrict__ Cb, const float* __restrict__ bias)
{
  __shared__ __align__(16) u16 As[128 * 32];
  __shared__ __align__(16) u16 Bs[64 * 32];
  const int tid = threadIdx.x;
  const int bm0 = blockIdx.y * 128;
  const int bn0 = blockIdx.x * 64;
  const int wid = tid >> 6, lane = tid & 63;
  const int lr = lane & 15, lk = lane >> 4;
  const int srow = tid >> 2, scol = (tid & 3) * 8;

  f32x4 zero4 = {0.f, 0.f, 0.f, 0.f};
  f32x4 acc[2][4];
#pragma unroll
  for (int m = 0; m < 2; ++m)
#pragma unroll
    for (int n = 0; n < 4; ++n) acc[m][n] = zero4;

  const u16* Ag = A + (size_t)(bm0 + srow) * Kdim + scol;
  const u16* Bg = B + (size_t)(bn0 + srow) * Kdim + scol;
  u16* AsP = As + srow * 32 + scol;
  u16* BsP = Bs + srow * 32 + scol;

  for (int k0 = 0; k0 < Kdim; k0 += 32) {
    gl_lds16(Ag + k0, AsP);
    gl_lds16(Ag + k0 + (size_t)64 * Kdim, AsP + 64 * 32);
    gl_lds16(Bg + k0, BsP);
    __syncthreads();
    short8 a[2], b[4];
#pragma unroll
    for (int m = 0; m < 2; ++m)
      a[m] = *(const short8*)(As + (wid * 32 + m * 16 + lr) * 32 + lk * 8);
#pragma unroll
    for (int n = 0; n < 4; ++n)
      b[n] = *(const short8*)(Bs + (n * 16 + lr) * 32 + lk * 8);
#pragma unroll
    for (int m = 0; m < 2; ++m)
#pragma unroll
      for (int n = 0; n < 4; ++n)
        acc[m][n] = __builtin_amdgcn_mfma_f32_16x16x32_bf16(a[m], b[n], acc[m][n], 0, 0, 0);
    __syncthreads();
  }

#pragma unroll
  for (int m = 0; m < 2; ++m)
#pragma unroll
    for (int n = 0; n < 4; ++n)
#pragma unroll
      for (int i = 0; i < 4; ++i) {
        int r = bm0 + wid * 32 + m * 16 + lk * 4 + i;
        int c = bn0 + n * 16 + lr;
        float v = acc[m][n][i] + bias[c];
        v = v / (1.f + expf(-v));
        Cb[(size_t)r * Ndim + c] = f2bf(v);
      }
}

// ---------------- fallback kernels (small-ws path) ----------------
__global__ __launch_bounds__(256, 2)
void k_down(const u16* __restrict__ A, const u16* __restrict__ B, float* __restrict__ C)
{
  __shared__ __align__(16) u16 As[128 * 32];
  __shared__ __align__(16) u16 Bs[128 * 32];
  const int bid = blockIdx.x;
  const int swz = (bid & 7) * 32 + (bid >> 3);
  const int bm0 = (swz >> 4) * 128;
  const int bn0 = (swz & 15) * 128;
  const int tid = threadIdx.x;
  const int wid = tid >> 6, lane = tid & 63;
  const int wr = (wid >> 1) * 64, wc = (wid & 1) * 64;
  const int lr = lane & 15, lk = lane >> 4;
  const int srow = tid >> 2, scol = (tid & 3) * 8;

  f32x4 zero4 = {0.f, 0.f, 0.f, 0.f};
  f32x4 acc[4][4];
#pragma unroll
  for (int m = 0; m < 4; ++m)
#pragma unroll
    for (int n = 0; n < 4; ++n) acc[m][n] = zero4;

  const u16* Ag = A + (size_t)(bm0 + srow) * EFD + scol;
  const u16* Bg = B + (size_t)(bn0 + srow) * EFD + scol;
  u16* AsP = As + srow * 32 + scol;
  u16* BsP = Bs + srow * 32 + scol;

  for (int k0 = 0; k0 < EFD; k0 += 32) {
    gl_lds16(Ag + k0, AsP);
    gl_lds16(Ag + k0 + (size_t)64 * EFD, AsP + 64 * 32);
    gl_lds16(Bg + k0, BsP);
    gl_lds16(Bg + k0 + (size_t)64 * EFD, BsP + 64 * 32);
    __syncthreads();
    short8 a[4], b[4];
#pragma unroll
    for (int m = 0; m < 4; ++m)
      a[m] = *(const short8*)(As + (wr + m * 16 + lr) * 32 + lk * 8);
#pragma unroll
    for (int n = 0; n < 4; ++n)
      b[n] = *(const short8*)(Bs + (wc + n * 16 + lr) * 32 + lk * 8);
#pragma unroll
    for (int m = 0; m < 4; ++m)
#pragma unroll
      for (int n = 0; n < 4; ++n)
        acc[m][n] = __builtin_amdgcn_mfma_f32_16x16x32_bf16(a[m], b[n], acc[m][n], 0, 0, 0);
    __syncthreads();
  }

#pragma unroll
  for (int m = 0; m < 4; ++m)
#pragma unroll
    for (int n = 0; n < 4; ++n)
#pragma unroll
      for (int i = 0; i < 4; ++i) {
        int r = bm0 + wr + m * 16 + lk * 4 + i;
        int c = bn0 + wc + n * 16 + lr;
        C[(size_t)r * H_DIM + c] = acc[m][n][i];
      }
}

__global__ __launch_bounds__(256, 2)
void k_gu_f32(const u16* __restrict__ Xbf, const float* __restrict__ Wg_, const float* __restrict__ Wu_,
              const int* __restrict__ list, const float* __restrict__ wlist,
              const int* __restrict__ counts, u16* __restrict__ actS)
{
  __shared__ __align__(16) u16 As[128 * 32];
  __shared__ __align__(16) u16 Gs[128 * 32];
  __shared__ __align__(16) u16 Us[128 * 32];
  const int e  = blockIdx.z;
  const int tb = blockIdx.y;
  if (tb * 128 >= counts[e]) return;
  const int f0 = blockIdx.x * 128;
  const int tid = threadIdx.x;
  const int wid = tid >> 6, lane = tid & 63;
  const int wr = (wid >> 1) * 64, wc = (wid & 1) * 64;
  const int lr = lane & 15, lk = lane >> 4;
  const int srow = tid >> 2, scol = (tid & 3) * 8;
  const int lbase = e * T_TOK + tb * 128;

  const int t0i = list[lbase + srow];
  const int t1i = list[lbase + 64 + srow];
  const u16* Ag0 = Xbf + (size_t)t0i * H_DIM + scol;
  const u16* Ag1 = Xbf + (size_t)t1i * H_DIM + scol;
  const size_t wrow = (size_t)(e * F_DIM + f0 + srow) * H_DIM + scol;

  f32x4 zero4 = {0.f, 0.f, 0.f, 0.f};
  f32x4 accg[4][4], accu[4][4];
#pragma unroll
  for (int m = 0; m < 4; ++m)
#pragma unroll
    for (int n = 0; n < 4; ++n) { accg[m][n] = zero4; accu[m][n] = zero4; }

  for (int k0 = 0; k0 < H_DIM; k0 += 32) {
    gl_lds16(Ag0 + k0, As + srow * 32 + scol);
    gl_lds16(Ag1 + k0, As + (64 + srow) * 32 + scol);
#pragma unroll
    for (int half = 0; half < 2; ++half) {
      size_t off = wrow + (size_t)(half * 64) * H_DIM + k0;
      float4 g0 = *(const float4*)(Wg_ + off), g1 = *(const float4*)(Wg_ + off + 4);
      float4 u0 = *(const float4*)(Wu_ + off), u1 = *(const float4*)(Wu_ + off + 4);
      union { short8 v; u16 ee[8]; } og, ou;
      og.ee[0] = f2bf(g0.x); og.ee[1] = f2bf(g0.y); og.ee[2] = f2bf(g0.z); og.ee[3] = f2bf(g0.w);
      og.ee[4] = f2bf(g1.x); og.ee[5] = f2bf(g1.y); og.ee[6] = f2bf(g1.z); og.ee[7] = f2bf(g1.w);
      ou.ee[0] = f2bf(u0.x); ou.ee[1] = f2bf(u0.y); ou.ee[2] = f2bf(u0.z); ou.ee[3] = f2bf(u0.w);
      ou.ee[4] = f2bf(u1.x); ou.ee[5] = f2bf(u1.y); ou.ee[6] = f2bf(u1.z); ou.ee[7] = f2bf(u1.w);
      *(short8*)(Gs + (half * 64 + srow) * 32 + scol) = og.v;
      *(short8*)(Us + (half * 64 + srow) * 32 + scol) = ou.v;
    }
    __syncthreads();
    short8 a[4], bg[4], bu[4];
#pragma unroll
    for (int m = 0; m < 4; ++m)
      a[m] = *(const short8*)(As + (wr + m * 16 + lr) * 32 + lk * 8);
#pragma unroll
    for (int n = 0; n < 4; ++n) {
      bg[n] = *(const short8*)(Gs + (wc + n * 16 + lr) * 32 + lk * 8);
      bu[n] = *(const short8*)(Us + (wc + n * 16 + lr) * 32 + lk * 8);
    }
#pragma unroll
    for (int m = 0; m < 4; ++m)
#pragma unroll
      for (int n = 0; n < 4; ++n) {
        accg[m][n] = __builtin_amdgcn_mfma_f32_16x16x32_bf16(a[m], bg[n], accg[m][n], 0, 0, 0);
        accu[m][n] = __builtin_amdgcn_mfma_f32_16x16x32_bf16(a[m], bu[n], accu[m][n], 0, 0, 0);
      }
    __syncthreads();
  }

#pragma unroll
  for (int m = 0; m < 4; ++m)
#pragma unroll
    for (int i = 0; i < 4; ++i) {
      int slot = tb * 128 + wr + m * 16 + lk * 4 + i;
      float w = wlist[e * T_TOK + slot];
      if (w > 0.f) {
        int t = list[e * T_TOK + slot];
        u16* dst = actS + (size_t)t * EFD + e * F_DIM + f0 + wc;
#pragma unroll
        for (int n = 0; n < 4; ++n) {
          float g = accg[m][n][i], u = accu[m][n][i];
          float act = w * (g / (1.f + expf(-g))) * u;
          dst[n * 16 + lr] = f2bf(act);
        }
      }
    }
}

// ---------------- per-token router (+ expert bitmask out) ----------------
__global__ void k_router(const float* __restrict__ x, const float* __restrict__ gu,
                         const u16* __restrict__ h1, const float* __restrict__ W2,
                         const float* __restrict__ b2, const float* __restrict__ gw,
                         const float* __restrict__ Umat, const float* __restrict__ alpha_p,
                         float* __restrict__ comb, unsigned* __restrict__ emask)
{
  __shared__ float xs[H_DIM];
  __shared__ float zbuf[8];
  __shared__ float rl[16];
  __shared__ int zi_s;
  const int t = blockIdx.x, tid = threadIdx.x;

  for (int i = tid; i < H_DIM / 4; i += 256)
    ((float4*)xs)[i] = ((const float4*)(x + (size_t)t * H_DIM))[i];

  int zg = tid >> 5, l32 = tid & 31;
  float zp = 0.f;
  const u16* h1r = h1 + (size_t)t * M_DIM;
  for (int j = l32; j < M_DIM; j += 32)
    zp += bf2f(h1r[j]) * W2[zg * M_DIM + j];
#pragma unroll
  for (int off = 16; off; off >>= 1) zp += __shfl_xor(zp, off);
  if (l32 == 0) zbuf[zg] = zp + b2[zg];
  __syncthreads();
  if (tid == 0) {
    float best = -1e30f; int bi = 0;
#pragma unroll
    for (int z = 0; z < 8; ++z) {
      float u = gu[t * 8 + z];
      float g = -logf(-logf(u + 1e-10f) + 1e-10f);
      float v = zbuf[z] + g;
      if (v > best) { best = v; bi = z; }
    }
    zi_s = bi;
  }
  __syncthreads();
  int eg = tid >> 4, l16 = tid & 15;
  float rp = 0.f;
  const float* gwr = gw + (size_t)eg * H_DIM;
  for (int j = l16; j < H_DIM; j += 16) rp += xs[j] * gwr[j];
#pragma unroll
  for (int off = 8; off; off >>= 1) rp += __shfl_xor(rp, off);
  if (l16 == 0) rl[eg] = rp;
  __syncthreads();
  if (tid == 0) {
    float a = alpha_p[0]; int zi = zi_s;
    float w[16], mx = -1e30f;
#pragma unroll
    for (int ee = 0; ee < 16; ++ee) { w[ee] = rl[ee] + a * Umat[zi * 16 + ee]; mx = fmaxf(mx, w[ee]); }
    float s = 0.f;
#pragma unroll
    for (int ee = 0; ee < 16; ++ee) { w[ee] = expf(w[ee] - mx); s += w[ee]; }
    float inv = 1.f / s;
    unsigned chosen = 0;
#pragma unroll
    for (int k = 0; k < 8; ++k) {
      float bw = -1.f; int bi = 0;
      for (int ee = 0; ee < 16; ++ee)
        if (!((chosen >> ee) & 1u) && w[ee] > bw) { bw = w[ee]; bi = ee; }
      chosen |= 1u << bi;
    }
    for (int ee = 0; ee < 16; ++ee)
      comb[t * 16 + ee] = ((chosen >> ee) & 1u) ? w[ee] * inv : 0.f;
    emask[t] = chosen;
  }
}

// ---------------- compaction (pad to 256) + tokmap fused ----------------
__global__ void k_compact(const float* __restrict__ comb, const unsigned* __restrict__ emask,
                          int* __restrict__ list, float* __restrict__ wlist,
                          int* __restrict__ counts, int* __restrict__ tokmap)
{
  __shared__ int sc[256];
  const int e = blockIdx.x, tid = threadIdx.x;
  int toks[8]; float ws[8]; int cnt = 0;
#pragma unroll
  for (int i = 0; i < 8; ++i) {
    int t = tid * 8 + i;
    float w = comb[t * E_NUM + e];
    if (w > 0.f) { toks[cnt] = t; ws[cnt] = w; ++cnt; }
  }
  sc[tid] = cnt;
  __syncthreads();
  for (int off = 1; off < 256; off <<= 1) {
    int v = (tid >= off) ? sc[tid - off] : 0;
    __syncthreads();
    sc[tid] += v;
    __syncthreads();
  }
  int base = sc[tid] - cnt;
  int total = sc[255];
  int padded = (total + 255) & ~255;
  int* lp = list + e * T_TOK;
  float* wp = wlist + e * T_TOK;
  for (int j = 0; j < cnt; ++j) {
    int t = toks[j];
    lp[base + j] = t; wp[base + j] = ws[j];
    int r = __popc(emask[t] & ((1u << e) - 1u));
    tokmap[t * 8 + r] = e * SLOTMAX + base + j;
  }
  for (int j = total + tid; j < padded; j += 256) { lp[j] = 0; wp[j] = 0.f; }
  if (tid == 0) counts[e] = padded;
}

extern "C" void kernel_launch(void* const* d_in, const int* in_sizes, int n_in,
                              void* d_out, int out_size, void* d_ws, size_t ws_size,
                              hipStream_t stream)
{
  const float* x  = (const float*)d_in[0];
  const float* gu = (const float*)d_in[1];
  const float* W1 = (const float*)d_in[2];
  const float* b1 = (const float*)d_in[3];
  const float* W2 = (const float*)d_in[4];
  const float* b2 = (const float*)d_in[5];
  const float* gw = (const float*)d_in[6];
  const float* Um = (const float*)d_in[7];
  const float* al = (const float*)d_in[8];
  const float* Wg = (const float*)d_in[9];
  const float* Wu = (const float*)d_in[10];
  const float* Wd = (const float*)d_in[11];
  float* y = (float*)d_out;

  size_t off = 0;
  char* base = (char*)d_ws;
  auto take = [&](size_t b) { char* p = base + off; off += (b + 255) & ~(size_t)255; return p; };
  u16*      x_bf   = (u16*)take((size_t)T_TOK * H_DIM * 2);
  u16*      W1_bf  = (u16*)take((size_t)M_DIM * H_DIM * 2);
  u16*      h1_bf  = (u16*)take((size_t)T_TOK * M_DIM * 2);
  float*    comb   = (float*)take((size_t)T_TOK * E_NUM * 4);
  int*      list   = (int*)take((size_t)E_NUM * T_TOK * 4);
  float*    wlist  = (float*)take((size_t)E_NUM * T_TOK * 4);
  int*      counts = (int*)take(64 * 4);
  unsigned* emask  = (unsigned*)take((size_t)T_TOK * 4);
  int*      tokmap = (int*)take((size_t)T_TOK * 8 * 4);
  u16*      actC   = (u16*)take((size_t)E_NUM * SLOTMAX * F_DIM * 2);   // 67MB (fb: dense actS)
  u16*      outE   = (u16*)take((size_t)E_NUM * SLOTMAX * H_DIM * 2);   // 134MB (fb: Wdp uses 67)
  u16*      Wg_bf  = (u16*)take((size_t)E_NUM * F_DIM * H_DIM * 2);
  u16*      Wu_bf  = (u16*)take((size_t)E_NUM * F_DIM * H_DIM * 2);
  u16*      Wd_bf  = (u16*)take((size_t)E_NUM * H_DIM * F_DIM * 2);
  bool big = (off <= ws_size);

  k_cvt<<<dim3((T_TOK * H_DIM / 8) / 256), 256, 0, stream>>>(x, x_bf, T_TOK * H_DIM / 8);
  k_cvt<<<dim3((M_DIM * H_DIM / 8) / 256), 256, 0, stream>>>(W1, W1_bf, M_DIM * H_DIM / 8);
  if (big)
    k_cvt3<<<dim3(49152), 256, 0, stream>>>(Wg, Wu, Wd, Wg_bf, Wu_bf, Wd_bf);

  k_gemm_h1<<<dim3(M_DIM / 64, T_TOK / 128), 256, 0, stream>>>(x_bf, W1_bf, M_DIM, H_DIM,
                                                               h1_bf, b1);
  k_router<<<dim3(T_TOK), 256, 0, stream>>>(x, gu, h1_bf, W2, b2, gw, Um, al, comb, emask);
  k_compact<<<dim3(E_NUM), 256, 0, stream>>>(comb, emask, list, wlist, counts, tokmap);

  if (big) {
    // fused gate+up -> compacted actC (grid.y=4, 2 bm0 reps per block: covers 0..2047)
    k8gu<<<dim3(F_DIM / 128, 4, E_NUM), 512, 131072, stream>>>(
        x_bf, Wg_bf, Wu_bf, list, wlist, counts, actC);
    // per-expert down -> outE (grid.y=4, 2 bm0 reps per block)
    k8d<<<dim3(H_DIM / 256, 4, E_NUM), 512, 131072, stream>>>(
        actC, Wd_bf, counts, outE);
    k_gather<<<dim3(T_TOK), 256, 0, stream>>>(outE, tokmap, y);
  } else {
    u16* actS = actC;
    u16* Wdp  = outE;
    k_cvt_wd<<<dim3(16384), 256, 0, stream>>>(Wd, Wdp);
    (void)hipMemsetAsync(actS, 0, (size_t)T_TOK * EFD * 2, stream);
    k_gu_f32<<<dim3(F_DIM / 128, 16, E_NUM), 256, 0, stream>>>(x_bf, Wg, Wu,
                                                               list, wlist, counts, actS);
    k_down<<<dim3(256), 256, 0, stream>>>(actS, Wdp, y);
  }
}

// Round 12
// 490.352 us; speedup vs baseline: 1.1644x; 1.1644x over previous
//
#include <hip/hip_runtime.h>
#include <math.h>

typedef unsigned short u16;
typedef __attribute__((ext_vector_type(8))) short short8;
typedef __attribute__((ext_vector_type(4))) float f32x4;

#define T_TOK 2048
#define H_DIM 2048
#define E_NUM 16
#define F_DIM 1024
#define EFD   16384
#define M_DIM 512
#define SLOTMAX 2048

__device__ __forceinline__ u16 f2bf(float x) {
  union { float f; unsigned u; } c; c.f = x;
  unsigned r = c.u + 0x7FFFu + ((c.u >> 16) & 1u);   // RNE
  return (u16)(r >> 16);
}
__device__ __forceinline__ float bf2f(u16 h) {
  union { unsigned u; float f; } c; c.u = ((unsigned)h) << 16;
  return c.f;
}
__device__ __forceinline__ void gl_lds16(const void* g, void* l) {
  __builtin_amdgcn_global_load_lds((const __attribute__((address_space(1))) void*)g,
                                   (__attribute__((address_space(3))) void*)l, 16, 0, 0);
}

// ---------------- conversion kernels ----------------
__global__ void k_cvt(const float* __restrict__ s, u16* __restrict__ d, int n8) {
  int i = blockIdx.x * 256 + threadIdx.x;
  if (i >= n8) return;
  const float4* sp = (const float4*)(s + (size_t)i * 8);
  float4 a = sp[0], b = sp[1];
  union { short8 v; u16 e[8]; } o;
  o.e[0] = f2bf(a.x); o.e[1] = f2bf(a.y); o.e[2] = f2bf(a.z); o.e[3] = f2bf(a.w);
  o.e[4] = f2bf(b.x); o.e[5] = f2bf(b.y); o.e[6] = f2bf(b.z); o.e[7] = f2bf(b.w);
  *(short8*)(d + (size_t)i * 8) = o.v;
}

// one launch: Wg, Wu, Wd fp32 -> bf16 (16384 blocks each)
__global__ void k_cvt3(const float* __restrict__ a, const float* __restrict__ b,
                       const float* __restrict__ c, u16* __restrict__ da,
                       u16* __restrict__ db, u16* __restrict__ dc) {
  int blk = blockIdx.x;
  const float* s; u16* d; int base;
  if (blk < 16384)      { s = a; d = da; base = blk; }
  else if (blk < 32768) { s = b; d = db; base = blk - 16384; }
  else                  { s = c; d = dc; base = blk - 32768; }
  int i = base * 256 + threadIdx.x;
  const float4* sp = (const float4*)(s + (size_t)i * 8);
  float4 va = sp[0], vb = sp[1];
  union { short8 v; u16 e[8]; } o;
  o.e[0] = f2bf(va.x); o.e[1] = f2bf(va.y); o.e[2] = f2bf(va.z); o.e[3] = f2bf(va.w);
  o.e[4] = f2bf(vb.x); o.e[5] = f2bf(vb.y); o.e[6] = f2bf(vb.z); o.e[7] = f2bf(vb.w);
  *(short8*)(d + (size_t)i * 8) = o.v;
}

// Wd[e,h,f] -> Wdp[h, e*F+f] (bf16)  [fallback path only]
__global__ void k_cvt_wd(const float* __restrict__ wd, u16* __restrict__ wdp) {
  int i = blockIdx.x * 256 + threadIdx.x;
  if (i >= (E_NUM * H_DIM * F_DIM) / 8) return;
  int f8 = i & 127;
  int h  = (i >> 7) & (H_DIM - 1);
  int e  = i >> 18;
  const float4* sp = (const float4*)(wd + (size_t)(e * H_DIM + h) * F_DIM + f8 * 8);
  float4 a = sp[0], b = sp[1];
  union { short8 v; u16 ee[8]; } o;
  o.ee[0] = f2bf(a.x); o.ee[1] = f2bf(a.y); o.ee[2] = f2bf(a.z); o.ee[3] = f2bf(a.w);
  o.ee[4] = f2bf(b.x); o.ee[5] = f2bf(b.y); o.ee[6] = f2bf(b.z); o.ee[7] = f2bf(b.w);
  *(short8*)(wdp + (size_t)h * EFD + e * F_DIM + f8 * 8) = o.v;
}

// ============ shared 8-phase machinery (identical schedule to R4/R6, verified) ============
#define STAGE8(s_, ab_, h_, t_) do {                                       \
    const u16* s0_ = srcp[ab_][h_][0] + (size_t)(t_) * 64;                 \
    const u16* s1_ = srcp[ab_][h_][1] + (size_t)(t_) * 64;                 \
    u16* d_ = lds + (((s_) * 2 + (ab_)) * 16384 + (h_) * 8192 + tid * 8);  \
    gl_lds16(s0_, d_); gl_lds16(s1_, d_ + 4096);                           \
  } while (0)

// ---------------- merged gate+up: actC[e][slot][f] = w*silu(g)*u ----------------
#define PHASE_GU(p_, STAGE_STMT, WAIT_STMT)                                       \
  {                                                                               \
    afr[0][0] = *(const short8*)(LA + (abase + (2*(p_)) * 1024));                 \
    afr[0][1] = *(const short8*)(LA + ((abase + (2*(p_)) * 1024) ^ 32));          \
    afr[1][0] = *(const short8*)(LA + (abase + (2*(p_)+1) * 1024));               \
    afr[1][1] = *(const short8*)(LA + ((abase + (2*(p_)+1) * 1024) ^ 32));        \
    if ((p_) == 0) {                                                              \
      _Pragma("unroll") for (int n = 0; n < 2; ++n) {                             \
        gfr[n][0] = *(const short8*)(LB + (bbase + n * 1024));                    \
        gfr[n][1] = *(const short8*)(LB + ((bbase + n * 1024) ^ 32));             \
        ufr[n][0] = *(const short8*)(LB + (8192 + bbase + n * 1024));             \
        ufr[n][1] = *(const short8*)(LB + ((8192 + bbase + n * 1024) ^ 32));      \
      }                                                                           \
    }                                                                             \
    STAGE_STMT; WAIT_STMT;                                                        \
    __builtin_amdgcn_s_barrier();                                                 \
    __builtin_amdgcn_s_setprio(1);                                                \
    _Pragma("unroll") for (int n = 0; n < 2; ++n)                                 \
      _Pragma("unroll") for (int kk = 0; kk < 2; ++kk) {                          \
        accg[2*(p_)][n]   = __builtin_amdgcn_mfma_f32_16x16x32_bf16(afr[0][kk], gfr[n][kk], accg[2*(p_)][n],   0,0,0); \
        accg[2*(p_)+1][n] = __builtin_amdgcn_mfma_f32_16x16x32_bf16(afr[1][kk], gfr[n][kk], accg[2*(p_)+1][n], 0,0,0); \
        accu[2*(p_)][n]   = __builtin_amdgcn_mfma_f32_16x16x32_bf16(afr[0][kk], ufr[n][kk], accu[2*(p_)][n],   0,0,0); \
        accu[2*(p_)+1][n] = __builtin_amdgcn_mfma_f32_16x16x32_bf16(afr[1][kk], ufr[n][kk], accu[2*(p_)+1][n], 0,0,0); \
      }                                                                           \
    __builtin_amdgcn_s_setprio(0);                                                \
    __builtin_amdgcn_s_barrier();                                                 \
  }

__global__ __launch_bounds__(512, 2)
void k8gu(const u16* __restrict__ Xbf, const u16* __restrict__ Wg, const u16* __restrict__ Wu,
          const int* __restrict__ list, const float* __restrict__ wlist,
          const int* __restrict__ counts, u16* __restrict__ actC)
{
  extern __shared__ u16 lds[];
  const int tid = threadIdx.x;
  const int wid = tid >> 6, lane = tid & 63;
  const int wm = wid >> 2, wn = wid & 3;       // wave tile: 128 slots x 32 cols
  const int lr = lane & 15, lk = lane >> 4;
  const int e = blockIdx.z;
  if ((int)blockIdx.y * 256 >= counts[e]) return;
  const int bm0 = blockIdx.y * 256;
  const int bn0 = blockIdx.x * 128;
  const int nt = H_DIM / 64;

  const int rl  = tid >> 3;
  const int csw = ((tid & 7) ^ (rl & 7)) * 8;
  const u16* srcp[2][2][2];
#pragma unroll
  for (int h = 0; h < 2; ++h)
#pragma unroll
    for (int c = 0; c < 2; ++c) {
      int ar = list[e * T_TOK + bm0 + h * 128 + c * 64 + rl];
      srcp[0][h][c] = Xbf + (size_t)ar * H_DIM + csw;
      size_t brow = (size_t)(e * F_DIM + bn0 + c * 64 + rl);
      srcp[1][h][c] = (h == 0 ? Wg : Wu) + brow * H_DIM + csw;
    }

  f32x4 accg[8][2], accu[8][2];
  f32x4 zero4 = {0.f, 0.f, 0.f, 0.f};
#pragma unroll
  for (int m = 0; m < 8; ++m)
#pragma unroll
    for (int n = 0; n < 2; ++n) { accg[m][n] = zero4; accu[m][n] = zero4; }

  STAGE8(0, 0, 0, 0); STAGE8(0, 0, 1, 0); STAGE8(0, 1, 0, 0); STAGE8(0, 1, 1, 0);
  STAGE8(1, 1, 0, 1); STAGE8(1, 1, 1, 1);
  asm volatile("s_waitcnt vmcnt(4)" ::: "memory");
  __builtin_amdgcn_s_barrier();

  const int abase = (wm * 128 + lr) * 64 + (lk ^ (lr & 7)) * 8;
  const int bbase = (wn * 32 + lr) * 64 + (lk ^ (lr & 7)) * 8;
  short8 afr[2][2], gfr[2][2], ufr[2][2];

  for (int t = 0; t < nt; ++t) {
    const int s = t & 1;
    const u16* LA = lds + (size_t)(s * 2) * 16384;
    const u16* LB = lds + (size_t)(s * 2 + 1) * 16384;
    PHASE_GU(0, if (t + 1 < nt) STAGE8(s ^ 1, 0, 0, t + 1), ((void)0));
    PHASE_GU(1, if (t + 1 < nt) STAGE8(s ^ 1, 0, 1, t + 1), ((void)0));
    PHASE_GU(2, if (t + 2 < nt) STAGE8(s, 1, 0, t + 2), ((void)0));
    PHASE_GU(3, if (t + 2 < nt) STAGE8(s, 1, 1, t + 2),
             if (t + 2 < nt) { asm volatile("s_waitcnt vmcnt(4)" ::: "memory"); }
             else            { asm volatile("s_waitcnt vmcnt(0)" ::: "memory"); });
    __builtin_amdgcn_sched_barrier(0);
  }

#pragma unroll
  for (int m = 0; m < 8; ++m)
#pragma unroll
    for (int i = 0; i < 4; ++i) {
      int slot = bm0 + wm * 128 + m * 16 + lk * 4 + i;
      float w = wlist[e * T_TOK + slot];
#pragma unroll
      for (int n = 0; n < 2; ++n) {
        int col = bn0 + wn * 32 + n * 16 + lr;
        float g = accg[m][n][i], u = accu[m][n][i];
        float act = w * (g / (1.f + expf(-g))) * u;
        actC[((size_t)e * SLOTMAX + slot) * F_DIM + col] = f2bf(act);
      }
    }
}

// ---------------- per-expert down: outE[e][slot][h] = actC_e @ Wd_e^T (bf16) ------------
#define PHASE_D(p_, STAGE_STMT, WAIT_STMT)                                        \
  {                                                                               \
    afr[0][0] = *(const short8*)(LA + (abase + (2*(p_)) * 1024));                 \
    afr[0][1] = *(const short8*)(LA + ((abase + (2*(p_)) * 1024) ^ 32));          \
    afr[1][0] = *(const short8*)(LA + (abase + (2*(p_)+1) * 1024));               \
    afr[1][1] = *(const short8*)(LA + ((abase + (2*(p_)+1) * 1024) ^ 32));        \
    if ((p_) == 0) {                                                              \
      _Pragma("unroll") for (int n = 0; n < 4; ++n) {                             \
        bfr[n][0] = *(const short8*)(LB + (bbase + n * 1024));                    \
        bfr[n][1] = *(const short8*)(LB + ((bbase + n * 1024) ^ 32));             \
      }                                                                           \
    }                                                                             \
    STAGE_STMT; WAIT_STMT;                                                        \
    __builtin_amdgcn_s_barrier();                                                 \
    __builtin_amdgcn_s_setprio(1);                                                \
    _Pragma("unroll") for (int n = 0; n < 4; ++n) {                               \
      acc[2*(p_)][n]   = __builtin_amdgcn_mfma_f32_16x16x32_bf16(afr[0][0], bfr[n][0], acc[2*(p_)][n],   0,0,0); \
      acc[2*(p_)][n]   = __builtin_amdgcn_mfma_f32_16x16x32_bf16(afr[0][1], bfr[n][1], acc[2*(p_)][n],   0,0,0); \
      acc[2*(p_)+1][n] = __builtin_amdgcn_mfma_f32_16x16x32_bf16(afr[1][0], bfr[n][0], acc[2*(p_)+1][n], 0,0,0); \
      acc[2*(p_)+1][n] = __builtin_amdgcn_mfma_f32_16x16x32_bf16(afr[1][1], bfr[n][1], acc[2*(p_)+1][n], 0,0,0); \
    }                                                                             \
    __builtin_amdgcn_s_setprio(0);                                                \
    __builtin_amdgcn_s_barrier();                                                 \
  }

__global__ __launch_bounds__(512, 2)
void k8d(const u16* __restrict__ actC, const u16* __restrict__ Wd,
         const int* __restrict__ counts, u16* __restrict__ outE)
{
  extern __shared__ u16 lds[];
  const int tid = threadIdx.x;
  const int wid = tid >> 6, lane = tid & 63;
  const int wm = wid >> 2, wn = wid & 3;       // wave tile: 128 slots x 64 h
  const int lr = lane & 15, lk = lane >> 4;
  const int e = blockIdx.z;
  if ((int)blockIdx.y * 256 >= counts[e]) return;
  const int bm0 = blockIdx.y * 256;
  const int bn0 = blockIdx.x * 256;
  const int nt = F_DIM / 64;

  const int rl  = tid >> 3;
  const int csw = ((tid & 7) ^ (rl & 7)) * 8;
  const u16* srcp[2][2][2];
#pragma unroll
  for (int h = 0; h < 2; ++h)
#pragma unroll
    for (int c = 0; c < 2; ++c) {
      srcp[0][h][c] = actC + ((size_t)e * SLOTMAX + bm0 + h * 128 + c * 64 + rl) * F_DIM + csw;
      srcp[1][h][c] = Wd + (size_t)e * H_DIM * F_DIM
                    + (size_t)(bn0 + h * 128 + c * 64 + rl) * F_DIM + csw;
    }

  f32x4 acc[8][4];
  f32x4 zero4 = {0.f, 0.f, 0.f, 0.f};
#pragma unroll
  for (int m = 0; m < 8; ++m)
#pragma unroll
    for (int n = 0; n < 4; ++n) acc[m][n] = zero4;

  STAGE8(0, 0, 0, 0); STAGE8(0, 0, 1, 0); STAGE8(0, 1, 0, 0); STAGE8(0, 1, 1, 0);
  STAGE8(1, 1, 0, 1); STAGE8(1, 1, 1, 1);
  asm volatile("s_waitcnt vmcnt(4)" ::: "memory");
  __builtin_amdgcn_s_barrier();

  const int abase = (wm * 128 + lr) * 64 + (lk ^ (lr & 7)) * 8;
  const int bbase = (wn * 64 + lr) * 64 + (lk ^ (lr & 7)) * 8;
  short8 afr[2][2], bfr[4][2];

  for (int t = 0; t < nt; ++t) {
    const int s = t & 1;
    const u16* LA = lds + (size_t)(s * 2) * 16384;
    const u16* LB = lds + (size_t)(s * 2 + 1) * 16384;
    PHASE_D(0, if (t + 1 < nt) STAGE8(s ^ 1, 0, 0, t + 1), ((void)0));
    PHASE_D(1, if (t + 1 < nt) STAGE8(s ^ 1, 0, 1, t + 1), ((void)0));
    PHASE_D(2, if (t + 2 < nt) STAGE8(s, 1, 0, t + 2), ((void)0));
    PHASE_D(3, if (t + 2 < nt) STAGE8(s, 1, 1, t + 2),
            if (t + 2 < nt) { asm volatile("s_waitcnt vmcnt(4)" ::: "memory"); }
            else            { asm volatile("s_waitcnt vmcnt(0)" ::: "memory"); });
    __builtin_amdgcn_sched_barrier(0);
  }

#pragma unroll
  for (int m = 0; m < 8; ++m)
#pragma unroll
    for (int n = 0; n < 4; ++n)
#pragma unroll
      for (int i = 0; i < 4; ++i) {
        int slot = bm0 + wm * 128 + m * 16 + lk * 4 + i;
        int col  = bn0 + wn * 64 + n * 16 + lr;
        outE[((size_t)e * SLOTMAX + slot) * H_DIM + col] = f2bf(acc[m][n][i]);
      }
}

// ---------------- gather-reduce: y[t,h] = sum_{r<8} outE[tokmap[t][r]][h] ----------------
__global__ void k_gather(const u16* __restrict__ outE, const int* __restrict__ tokmap,
                         float* __restrict__ y)
{
  __shared__ int tm[8];
  const int t = blockIdx.x, tid = threadIdx.x;
  if (tid < 8) tm[tid] = tokmap[t * 8 + tid];
  __syncthreads();
  float s[8] = {0.f, 0.f, 0.f, 0.f, 0.f, 0.f, 0.f, 0.f};
#pragma unroll
  for (int r = 0; r < 8; ++r) {
    union { short8 v; u16 e[8]; } row;
    row.v = *(const short8*)(outE + (size_t)tm[r] * H_DIM + tid * 8);
#pragma unroll
    for (int j = 0; j < 8; ++j) s[j] += bf2f(row.e[j]);
  }
  float* dst = y + (size_t)t * H_DIM + tid * 8;
#pragma unroll
  for (int j = 0; j < 8; ++j) dst[j] = s[j];
}

// ---------------- small GEMM for h1: C = silu(A*B^T + bias) -> bf16 ----------------
__global__ __launch_bounds__(256, 2)
void k_gemm_h1(const u16* __restrict__ A, const u16* __restrict__ B, int Ndim, int Kdim,
               u16* __restrict__ Cb, const float* __restrict__ bias)
{
  __shared__ __align__(16) u16 As[128 * 32];
  __shared__ __align__(16) u16 Bs[64 * 32];
  const int tid = threadIdx.x;
  const int bm0 = blockIdx.y * 128;
  const int bn0 = blockIdx.x * 64;
  const int wid = tid >> 6, lane = tid & 63;
  const int lr = lane & 15, lk = lane >> 4;
  const int srow = tid >> 2, scol = (tid & 3) * 8;

  f32x4 zero4 = {0.f, 0.f, 0.f, 0.f};
  f32x4 acc[2][4];
#pragma unroll
  for (int m = 0; m < 2; ++m)
#pragma unroll
    for (int n = 0; n < 4; ++n) acc[m][n] = zero4;

  const u16* Ag = A + (size_t)(bm0 + srow) * Kdim + scol;
  const u16* Bg = B + (size_t)(bn0 + srow) * Kdim + scol;
  u16* AsP = As + srow * 32 + scol;
  u16* BsP = Bs + srow * 32 + scol;

  for (int k0 = 0; k0 < Kdim; k0 += 32) {
    gl_lds16(Ag + k0, AsP);
    gl_lds16(Ag + k0 + (size_t)64 * Kdim, AsP + 64 * 32);
    gl_lds16(Bg + k0, BsP);
    __syncthreads();
    short8 a[2], b[4];
#pragma unroll
    for (int m = 0; m < 2; ++m)
      a[m] = *(const short8*)(As + (wid * 32 + m * 16 + lr) * 32 + lk * 8);
#pragma unroll
    for (int n = 0; n < 4; ++n)
      b[n] = *(const short8*)(Bs + (n * 16 + lr) * 32 + lk * 8);
#pragma unroll
    for (int m = 0; m < 2; ++m)
#pragma unroll
      for (int n = 0; n < 4; ++n)
        acc[m][n] = __builtin_amdgcn_mfma_f32_16x16x32_bf16(a[m], b[n], acc[m][n], 0, 0, 0);
    __syncthreads();
  }

#pragma unroll
  for (int m = 0; m < 2; ++m)
#pragma unroll
    for (int n = 0; n < 4; ++n)
#pragma unroll
      for (int i = 0; i < 4; ++i) {
        int r = bm0 + wid * 32 + m * 16 + lk * 4 + i;
        int c = bn0 + n * 16 + lr;
        float v = acc[m][n][i] + bias[c];
        v = v / (1.f + expf(-v));
        Cb[(size_t)r * Ndim + c] = f2bf(v);
      }
}

// ---------------- fallback kernels (small-ws path) ----------------
__global__ __launch_bounds__(256, 2)
void k_down(const u16* __restrict__ A, const u16* __restrict__ B, float* __restrict__ C)
{
  __shared__ __align__(16) u16 As[128 * 32];
  __shared__ __align__(16) u16 Bs[128 * 32];
  const int bid = blockIdx.x;
  const int swz = (bid & 7) * 32 + (bid >> 3);
  const int bm0 = (swz >> 4) * 128;
  const int bn0 = (swz & 15) * 128;
  const int tid = threadIdx.x;
  const int wid = tid >> 6, lane = tid & 63;
  const int wr = (wid >> 1) * 64, wc = (wid & 1) * 64;
  const int lr = lane & 15, lk = lane >> 4;
  const int srow = tid >> 2, scol = (tid & 3) * 8;

  f32x4 zero4 = {0.f, 0.f, 0.f, 0.f};
  f32x4 acc[4][4];
#pragma unroll
  for (int m = 0; m < 4; ++m)
#pragma unroll
    for (int n = 0; n < 4; ++n) acc[m][n] = zero4;

  const u16* Ag = A + (size_t)(bm0 + srow) * EFD + scol;
  const u16* Bg = B + (size_t)(bn0 + srow) * EFD + scol;
  u16* AsP = As + srow * 32 + scol;
  u16* BsP = Bs + srow * 32 + scol;

  for (int k0 = 0; k0 < EFD; k0 += 32) {
    gl_lds16(Ag + k0, AsP);
    gl_lds16(Ag + k0 + (size_t)64 * EFD, AsP + 64 * 32);
    gl_lds16(Bg + k0, BsP);
    gl_lds16(Bg + k0 + (size_t)64 * EFD, BsP + 64 * 32);
    __syncthreads();
    short8 a[4], b[4];
#pragma unroll
    for (int m = 0; m < 4; ++m)
      a[m] = *(const short8*)(As + (wr + m * 16 + lr) * 32 + lk * 8);
#pragma unroll
    for (int n = 0; n < 4; ++n)
      b[n] = *(const short8*)(Bs + (wc + n * 16 + lr) * 32 + lk * 8);
#pragma unroll
    for (int m = 0; m < 4; ++m)
#pragma unroll
      for (int n = 0; n < 4; ++n)
        acc[m][n] = __builtin_amdgcn_mfma_f32_16x16x32_bf16(a[m], b[n], acc[m][n], 0, 0, 0);
    __syncthreads();
  }

#pragma unroll
  for (int m = 0; m < 4; ++m)
#pragma unroll
    for (int n = 0; n < 4; ++n)
#pragma unroll
      for (int i = 0; i < 4; ++i) {
        int r = bm0 + wr + m * 16 + lk * 4 + i;
        int c = bn0 + wc + n * 16 + lr;
        C[(size_t)r * H_DIM + c] = acc[m][n][i];
      }
}

__global__ __launch_bounds__(256, 2)
void k_gu_f32(const u16* __restrict__ Xbf, const float* __restrict__ Wg_, const float* __restrict__ Wu_,
              const int* __restrict__ list, const float* __restrict__ wlist,
              const int* __restrict__ counts, u16* __restrict__ actS)
{
  __shared__ __align__(16) u16 As[128 * 32];
  __shared__ __align__(16) u16 Gs[128 * 32];
  __shared__ __align__(16) u16 Us[128 * 32];
  const int e  = blockIdx.z;
  const int tb = blockIdx.y;
  if (tb * 128 >= counts[e]) return;
  const int f0 = blockIdx.x * 128;
  const int tid = threadIdx.x;
  const int wid = tid >> 6, lane = tid & 63;
  const int wr = (wid >> 1) * 64, wc = (wid & 1) * 64;
  const int lr = lane & 15, lk = lane >> 4;
  const int srow = tid >> 2, scol = (tid & 3) * 8;
  const int lbase = e * T_TOK + tb * 128;

  const int t0i = list[lbase + srow];
  const int t1i = list[lbase + 64 + srow];
  const u16* Ag0 = Xbf + (size_t)t0i * H_DIM + scol;
  const u16* Ag1 = Xbf + (size_t)t1i * H_DIM + scol;
  const size_t wrow = (size_t)(e * F_DIM + f0 + srow) * H_DIM + scol;

  f32x4 zero4 = {0.f, 0.f, 0.f, 0.f};
  f32x4 accg[4][4], accu[4][4];
#pragma unroll
  for (int m = 0; m < 4; ++m)
#pragma unroll
    for (int n = 0; n < 4; ++n) { accg[m][n] = zero4; accu[m][n] = zero4; }

  for (int k0 = 0; k0 < H_DIM; k0 += 32) {
    gl_lds16(Ag0 + k0, As + srow * 32 + scol);
    gl_lds16(Ag1 + k0, As + (64 + srow) * 32 + scol);
#pragma unroll
    for (int half = 0; half < 2; ++half) {
      size_t off = wrow + (size_t)(half * 64) * H_DIM + k0;
      float4 g0 = *(const float4*)(Wg_ + off), g1 = *(const float4*)(Wg_ + off + 4);
      float4 u0 = *(const float4*)(Wu_ + off), u1 = *(const float4*)(Wu_ + off + 4);
      union { short8 v; u16 ee[8]; } og, ou;
      og.ee[0] = f2bf(g0.x); og.ee[1] = f2bf(g0.y); og.ee[2] = f2bf(g0.z); og.ee[3] = f2bf(g0.w);
      og.ee[4] = f2bf(g1.x); og.ee[5] = f2bf(g1.y); og.ee[6] = f2bf(g1.z); og.ee[7] = f2bf(g1.w);
      ou.ee[0] = f2bf(u0.x); ou.ee[1] = f2bf(u0.y); ou.ee[2] = f2bf(u0.z); ou.ee[3] = f2bf(u0.w);
      ou.ee[4] = f2bf(u1.x); ou.ee[5] = f2bf(u1.y); ou.ee[6] = f2bf(u1.z); ou.ee[7] = f2bf(u1.w);
      *(short8*)(Gs + (half * 64 + srow) * 32 + scol) = og.v;
      *(short8*)(Us + (half * 64 + srow) * 32 + scol) = ou.v;
    }
    __syncthreads();
    short8 a[4], bg[4], bu[4];
#pragma unroll
    for (int m = 0; m < 4; ++m)
      a[m] = *(const short8*)(As + (wr + m * 16 + lr) * 32 + lk * 8);
#pragma unroll
    for (int n = 0; n < 4; ++n) {
      bg[n] = *(const short8*)(Gs + (wc + n * 16 + lr) * 32 + lk * 8);
      bu[n] = *(const short8*)(Us + (wc + n * 16 + lr) * 32 + lk * 8);
    }
#pragma unroll
    for (int m = 0; m < 4; ++m)
#pragma unroll
      for (int n = 0; n < 4; ++n) {
        accg[m][n] = __builtin_amdgcn_mfma_f32_16x16x32_bf16(a[m], bg[n], accg[m][n], 0, 0, 0);
        accu[m][n] = __builtin_amdgcn_mfma_f32_16x16x32_bf16(a[m], bu[n], accu[m][n], 0, 0, 0);
      }
    __syncthreads();
  }

#pragma unroll
  for (int m = 0; m < 4; ++m)
#pragma unroll
    for (int i = 0; i < 4; ++i) {
      int slot = tb * 128 + wr + m * 16 + lk * 4 + i;
      float w = wlist[e * T_TOK + slot];
      if (w > 0.f) {
        int t = list[e * T_TOK + slot];
        u16* dst = actS + (size_t)t * EFD + e * F_DIM + f0 + wc;
#pragma unroll
        for (int n = 0; n < 4; ++n) {
          float g = accg[m][n][i], u = accu[m][n][i];
          float act = w * (g / (1.f + expf(-g))) * u;
          dst[n * 16 + lr] = f2bf(act);
        }
      }
    }
}

// ---------------- per-token router (+ expert bitmask out) ----------------
__global__ void k_router(const float* __restrict__ x, const float* __restrict__ gu,
                         const u16* __restrict__ h1, const float* __restrict__ W2,
                         const float* __restrict__ b2, const float* __restrict__ gw,
                         const float* __restrict__ Umat, const float* __restrict__ alpha_p,
                         float* __restrict__ comb, unsigned* __restrict__ emask)
{
  __shared__ float xs[H_DIM];
  __shared__ float zbuf[8];
  __shared__ float rl[16];
  __shared__ int zi_s;
  const int t = blockIdx.x, tid = threadIdx.x;

  for (int i = tid; i < H_DIM / 4; i += 256)
    ((float4*)xs)[i] = ((const float4*)(x + (size_t)t * H_DIM))[i];

  int zg = tid >> 5, l32 = tid & 31;
  float zp = 0.f;
  const u16* h1r = h1 + (size_t)t * M_DIM;
  for (int j = l32; j < M_DIM; j += 32)
    zp += bf2f(h1r[j]) * W2[zg * M_DIM + j];
#pragma unroll
  for (int off = 16; off; off >>= 1) zp += __shfl_xor(zp, off);
  if (l32 == 0) zbuf[zg] = zp + b2[zg];
  __syncthreads();
  if (tid == 0) {
    float best = -1e30f; int bi = 0;
#pragma unroll
    for (int z = 0; z < 8; ++z) {
      float u = gu[t * 8 + z];
      float g = -logf(-logf(u + 1e-10f) + 1e-10f);
      float v = zbuf[z] + g;
      if (v > best) { best = v; bi = z; }
    }
    zi_s = bi;
  }
  __syncthreads();
  int eg = tid >> 4, l16 = tid & 15;
  float rp = 0.f;
  const float* gwr = gw + (size_t)eg * H_DIM;
  for (int j = l16; j < H_DIM; j += 16) rp += xs[j] * gwr[j];
#pragma unroll
  for (int off = 8; off; off >>= 1) rp += __shfl_xor(rp, off);
  if (l16 == 0) rl[eg] = rp;
  __syncthreads();
  if (tid == 0) {
    float a = alpha_p[0]; int zi = zi_s;
    float w[16], mx = -1e30f;
#pragma unroll
    for (int ee = 0; ee < 16; ++ee) { w[ee] = rl[ee] + a * Umat[zi * 16 + ee]; mx = fmaxf(mx, w[ee]); }
    float s = 0.f;
#pragma unroll
    for (int ee = 0; ee < 16; ++ee) { w[ee] = expf(w[ee] - mx); s += w[ee]; }
    float inv = 1.f / s;
    unsigned chosen = 0;
#pragma unroll
    for (int k = 0; k < 8; ++k) {
      float bw = -1.f; int bi = 0;
      for (int ee = 0; ee < 16; ++ee)
        if (!((chosen >> ee) & 1u) && w[ee] > bw) { bw = w[ee]; bi = ee; }
      chosen |= 1u << bi;
    }
    for (int ee = 0; ee < 16; ++ee)
      comb[t * 16 + ee] = ((chosen >> ee) & 1u) ? w[ee] * inv : 0.f;
    emask[t] = chosen;
  }
}

// ---------------- compaction (pad to 256) + tokmap fused ----------------
__global__ void k_compact(const float* __restrict__ comb, const unsigned* __restrict__ emask,
                          int* __restrict__ list, float* __restrict__ wlist,
                          int* __restrict__ counts, int* __restrict__ tokmap)
{
  __shared__ int sc[256];
  const int e = blockIdx.x, tid = threadIdx.x;
  int toks[8]; float ws[8]; int cnt = 0;
#pragma unroll
  for (int i = 0; i < 8; ++i) {
    int t = tid * 8 + i;
    float w = comb[t * E_NUM + e];
    if (w > 0.f) { toks[cnt] = t; ws[cnt] = w; ++cnt; }
  }
  sc[tid] = cnt;
  __syncthreads();
  for (int off = 1; off < 256; off <<= 1) {
    int v = (tid >= off) ? sc[tid - off] : 0;
    __syncthreads();
    sc[tid] += v;
    __syncthreads();
  }
  int base = sc[tid] - cnt;
  int total = sc[255];
  int padded = (total + 255) & ~255;
  int* lp = list + e * T_TOK;
  float* wp = wlist + e * T_TOK;
  for (int j = 0; j < cnt; ++j) {
    int t = toks[j];
    lp[base + j] = t; wp[base + j] = ws[j];
    int r = __popc(emask[t] & ((1u << e) - 1u));
    tokmap[t * 8 + r] = e * SLOTMAX + base + j;
  }
  for (int j = total + tid; j < padded; j += 256) { lp[j] = 0; wp[j] = 0.f; }
  if (tid == 0) counts[e] = padded;
}

extern "C" void kernel_launch(void* const* d_in, const int* in_sizes, int n_in,
                              void* d_out, int out_size, void* d_ws, size_t ws_size,
                              hipStream_t stream)
{
  const float* x  = (const float*)d_in[0];
  const float* gu = (const float*)d_in[1];
  const float* W1 = (const float*)d_in[2];
  const float* b1 = (const float*)d_in[3];
  const float* W2 = (const float*)d_in[4];
  const float* b2 = (const float*)d_in[5];
  const float* gw = (const float*)d_in[6];
  const float* Um = (const float*)d_in[7];
  const float* al = (const float*)d_in[8];
  const float* Wg = (const float*)d_in[9];
  const float* Wu = (const float*)d_in[10];
  const float* Wd = (const float*)d_in[11];
  float* y = (float*)d_out;

  size_t off = 0;
  char* base = (char*)d_ws;
  auto take = [&](size_t b) { char* p = base + off; off += (b + 255) & ~(size_t)255; return p; };
  u16*      x_bf   = (u16*)take((size_t)T_TOK * H_DIM * 2);
  u16*      W1_bf  = (u16*)take((size_t)M_DIM * H_DIM * 2);
  u16*      h1_bf  = (u16*)take((size_t)T_TOK * M_DIM * 2);
  float*    comb   = (float*)take((size_t)T_TOK * E_NUM * 4);
  int*      list   = (int*)take((size_t)E_NUM * T_TOK * 4);
  float*    wlist  = (float*)take((size_t)E_NUM * T_TOK * 4);
  int*      counts = (int*)take(64 * 4);
  unsigned* emask  = (unsigned*)take((size_t)T_TOK * 4);
  int*      tokmap = (int*)take((size_t)T_TOK * 8 * 4);
  u16*      actC   = (u16*)take((size_t)E_NUM * SLOTMAX * F_DIM * 2);   // 67MB (fb: dense actS)
  u16*      outE   = (u16*)take((size_t)E_NUM * SLOTMAX * H_DIM * 2);   // 134MB (fb: Wdp uses 67)
  u16*      Wg_bf  = (u16*)take((size_t)E_NUM * F_DIM * H_DIM * 2);
  u16*      Wu_bf  = (u16*)take((size_t)E_NUM * F_DIM * H_DIM * 2);
  u16*      Wd_bf  = (u16*)take((size_t)E_NUM * H_DIM * F_DIM * 2);
  bool big = (off <= ws_size);

  k_cvt<<<dim3((T_TOK * H_DIM / 8) / 256), 256, 0, stream>>>(x, x_bf, T_TOK * H_DIM / 8);
  k_cvt<<<dim3((M_DIM * H_DIM / 8) / 256), 256, 0, stream>>>(W1, W1_bf, M_DIM * H_DIM / 8);
  if (big)
    k_cvt3<<<dim3(49152), 256, 0, stream>>>(Wg, Wu, Wd, Wg_bf, Wu_bf, Wd_bf);

  k_gemm_h1<<<dim3(M_DIM / 64, T_TOK / 128), 256, 0, stream>>>(x_bf, W1_bf, M_DIM, H_DIM,
                                                               h1_bf, b1);
  k_router<<<dim3(T_TOK), 256, 0, stream>>>(x, gu, h1_bf, W2, b2, gw, Um, al, comb, emask);
  k_compact<<<dim3(E_NUM), 256, 0, stream>>>(comb, emask, list, wlist, counts, tokmap);

  if (big) {
    // fused gate+up -> compacted actC (R6 geometry: 1024 blocks)
    k8gu<<<dim3(F_DIM / 128, SLOTMAX / 256, E_NUM), 512, 131072, stream>>>(
        x_bf, Wg_bf, Wu_bf, list, wlist, counts, actC);
    // per-expert down -> outE (R6 geometry: 512 blocks)
    k8d<<<dim3(H_DIM / 256, SLOTMAX / 256, E_NUM), 512, 131072, stream>>>(
        actC, Wd_bf, counts, outE);
    k_gather<<<dim3(T_TOK), 256, 0, stream>>>(outE, tokmap, y);
  } else {
    u16* actS = actC;
    u16* Wdp  = outE;
    k_cvt_wd<<<dim3(16384), 256, 0, stream>>>(Wd, Wdp);
    (void)hipMemsetAsync(actS, 0, (size_t)T_TOK * EFD * 2, stream);
    k_gu_f32<<<dim3(F_DIM / 128, 16, E_NUM), 256, 0, stream>>>(x_bf, Wg, Wu,
                                                               list, wlist, counts, actS);
    k_down<<<dim3(256), 256, 0, stream>>>(actS, Wdp, y);
  }
}

// Round 13
// 484.854 us; speedup vs baseline: 1.1776x; 1.0113x over previous
//
#include <hip/hip_runtime.h>
#include <math.h>

typedef unsigned short u16;
typedef __attribute__((ext_vector_type(8))) short short8;
typedef __attribute__((ext_vector_type(4))) float f32x4;

#define T_TOK 2048
#define H_DIM 2048
#define E_NUM 16
#define F_DIM 1024
#define EFD   16384
#define M_DIM 512
#define SLOTMAX 2048

__device__ __forceinline__ u16 f2bf(float x) {
  union { float f; unsigned u; } c; c.f = x;
  unsigned r = c.u + 0x7FFFu + ((c.u >> 16) & 1u);   // RNE
  return (u16)(r >> 16);
}
__device__ __forceinline__ float bf2f(u16 h) {
  union { unsigned u; float f; } c; c.u = ((unsigned)h) << 16;
  return c.f;
}
__device__ __forceinline__ void gl_lds16(const void* g, void* l) {
  __builtin_amdgcn_global_load_lds((const __attribute__((address_space(1))) void*)g,
                                   (__attribute__((address_space(3))) void*)l, 16, 0, 0);
}

// ---------------- conversion kernels ----------------
__global__ void k_cvt(const float* __restrict__ s, u16* __restrict__ d, int n8) {
  int i = blockIdx.x * 256 + threadIdx.x;
  if (i >= n8) return;
  const float4* sp = (const float4*)(s + (size_t)i * 8);
  float4 a = sp[0], b = sp[1];
  union { short8 v; u16 e[8]; } o;
  o.e[0] = f2bf(a.x); o.e[1] = f2bf(a.y); o.e[2] = f2bf(a.z); o.e[3] = f2bf(a.w);
  o.e[4] = f2bf(b.x); o.e[5] = f2bf(b.y); o.e[6] = f2bf(b.z); o.e[7] = f2bf(b.w);
  *(short8*)(d + (size_t)i * 8) = o.v;
}

// one launch: x, W1, Wg, Wu fp32 -> bf16
// block ranges: [0,2048) x | [2048,2560) W1 | [2560,18944) Wg | [18944,35328) Wu
__global__ void k_cvt_all(const float* __restrict__ x, const float* __restrict__ W1,
                          const float* __restrict__ Wg, const float* __restrict__ Wu,
                          u16* __restrict__ xb, u16* __restrict__ w1b,
                          u16* __restrict__ wgb, u16* __restrict__ wub) {
  int blk = blockIdx.x;
  const float* s; u16* d; int base;
  if (blk < 2048)       { s = x;  d = xb;  base = blk; }
  else if (blk < 2560)  { s = W1; d = w1b; base = blk - 2048; }
  else if (blk < 18944) { s = Wg; d = wgb; base = blk - 2560; }
  else                  { s = Wu; d = wub; base = blk - 18944; }
  int i = base * 256 + threadIdx.x;
  const float4* sp = (const float4*)(s + (size_t)i * 8);
  float4 va = sp[0], vb = sp[1];
  union { short8 v; u16 e[8]; } o;
  o.e[0] = f2bf(va.x); o.e[1] = f2bf(va.y); o.e[2] = f2bf(va.z); o.e[3] = f2bf(va.w);
  o.e[4] = f2bf(vb.x); o.e[5] = f2bf(vb.y); o.e[6] = f2bf(vb.z); o.e[7] = f2bf(vb.w);
  *(short8*)(d + (size_t)i * 8) = o.v;
}

// Wd[e,h,f] -> Wdp[h, e*F+f] (bf16)  [fallback path only]
__global__ void k_cvt_wd(const float* __restrict__ wd, u16* __restrict__ wdp) {
  int i = blockIdx.x * 256 + threadIdx.x;
  if (i >= (E_NUM * H_DIM * F_DIM) / 8) return;
  int f8 = i & 127;
  int h  = (i >> 7) & (H_DIM - 1);
  int e  = i >> 18;
  const float4* sp = (const float4*)(wd + (size_t)(e * H_DIM + h) * F_DIM + f8 * 8);
  float4 a = sp[0], b = sp[1];
  union { short8 v; u16 ee[8]; } o;
  o.ee[0] = f2bf(a.x); o.ee[1] = f2bf(a.y); o.ee[2] = f2bf(a.z); o.ee[3] = f2bf(a.w);
  o.ee[4] = f2bf(b.x); o.ee[5] = f2bf(b.y); o.ee[6] = f2bf(b.z); o.ee[7] = f2bf(b.w);
  *(short8*)(wdp + (size_t)h * EFD + e * F_DIM + f8 * 8) = o.v;
}

// ============ shared 8-phase machinery (identical schedule to R4/R6, verified) ============
#define STAGE8(s_, ab_, h_, t_) do {                                       \
    const u16* s0_ = srcp[ab_][h_][0] + (size_t)(t_) * 64;                 \
    const u16* s1_ = srcp[ab_][h_][1] + (size_t)(t_) * 64;                 \
    u16* d_ = lds + (((s_) * 2 + (ab_)) * 16384 + (h_) * 8192 + tid * 8);  \
    gl_lds16(s0_, d_); gl_lds16(s1_, d_ + 4096);                           \
  } while (0)

// ---------------- merged gate+up: actC[e][slot][f] = w*silu(g)*u ----------------
#define PHASE_GU(p_, STAGE_STMT, WAIT_STMT)                                       \
  {                                                                               \
    afr[0][0] = *(const short8*)(LA + (abase + (2*(p_)) * 1024));                 \
    afr[0][1] = *(const short8*)(LA + ((abase + (2*(p_)) * 1024) ^ 32));          \
    afr[1][0] = *(const short8*)(LA + (abase + (2*(p_)+1) * 1024));               \
    afr[1][1] = *(const short8*)(LA + ((abase + (2*(p_)+1) * 1024) ^ 32));        \
    if ((p_) == 0) {                                                              \
      _Pragma("unroll") for (int n = 0; n < 2; ++n) {                             \
        gfr[n][0] = *(const short8*)(LB + (bbase + n * 1024));                    \
        gfr[n][1] = *(const short8*)(LB + ((bbase + n * 1024) ^ 32));             \
        ufr[n][0] = *(const short8*)(LB + (8192 + bbase + n * 1024));             \
        ufr[n][1] = *(const short8*)(LB + ((8192 + bbase + n * 1024) ^ 32));      \
      }                                                                           \
    }                                                                             \
    STAGE_STMT; WAIT_STMT;                                                        \
    __builtin_amdgcn_s_barrier();                                                 \
    __builtin_amdgcn_s_setprio(1);                                                \
    _Pragma("unroll") for (int n = 0; n < 2; ++n)                                 \
      _Pragma("unroll") for (int kk = 0; kk < 2; ++kk) {                          \
        accg[2*(p_)][n]   = __builtin_amdgcn_mfma_f32_16x16x32_bf16(afr[0][kk], gfr[n][kk], accg[2*(p_)][n],   0,0,0); \
        accg[2*(p_)+1][n] = __builtin_amdgcn_mfma_f32_16x16x32_bf16(afr[1][kk], gfr[n][kk], accg[2*(p_)+1][n], 0,0,0); \
        accu[2*(p_)][n]   = __builtin_amdgcn_mfma_f32_16x16x32_bf16(afr[0][kk], ufr[n][kk], accu[2*(p_)][n],   0,0,0); \
        accu[2*(p_)+1][n] = __builtin_amdgcn_mfma_f32_16x16x32_bf16(afr[1][kk], ufr[n][kk], accu[2*(p_)+1][n], 0,0,0); \
      }                                                                           \
    __builtin_amdgcn_s_setprio(0);                                                \
    __builtin_amdgcn_s_barrier();                                                 \
  }

__global__ __launch_bounds__(512, 2)
void k8gu(const u16* __restrict__ Xbf, const u16* __restrict__ Wg, const u16* __restrict__ Wu,
          const int* __restrict__ list, const float* __restrict__ wlist,
          const int* __restrict__ counts, u16* __restrict__ actC)
{
  extern __shared__ u16 lds[];
  const int tid = threadIdx.x;
  const int wid = tid >> 6, lane = tid & 63;
  const int wm = wid >> 2, wn = wid & 3;       // wave tile: 128 slots x 32 cols
  const int lr = lane & 15, lk = lane >> 4;
  const int e = blockIdx.z;
  if ((int)blockIdx.y * 256 >= counts[e]) return;
  const int bm0 = blockIdx.y * 256;
  const int bn0 = blockIdx.x * 128;
  const int nt = H_DIM / 64;

  const int rl  = tid >> 3;
  const int csw = ((tid & 7) ^ (rl & 7)) * 8;
  const u16* srcp[2][2][2];
#pragma unroll
  for (int h = 0; h < 2; ++h)
#pragma unroll
    for (int c = 0; c < 2; ++c) {
      int ar = list[e * T_TOK + bm0 + h * 128 + c * 64 + rl];
      srcp[0][h][c] = Xbf + (size_t)ar * H_DIM + csw;
      size_t brow = (size_t)(e * F_DIM + bn0 + c * 64 + rl);
      srcp[1][h][c] = (h == 0 ? Wg : Wu) + brow * H_DIM + csw;
    }

  f32x4 accg[8][2], accu[8][2];
  f32x4 zero4 = {0.f, 0.f, 0.f, 0.f};
#pragma unroll
  for (int m = 0; m < 8; ++m)
#pragma unroll
    for (int n = 0; n < 2; ++n) { accg[m][n] = zero4; accu[m][n] = zero4; }

  STAGE8(0, 0, 0, 0); STAGE8(0, 0, 1, 0); STAGE8(0, 1, 0, 0); STAGE8(0, 1, 1, 0);
  STAGE8(1, 1, 0, 1); STAGE8(1, 1, 1, 1);
  asm volatile("s_waitcnt vmcnt(4)" ::: "memory");
  __builtin_amdgcn_s_barrier();

  const int abase = (wm * 128 + lr) * 64 + (lk ^ (lr & 7)) * 8;
  const int bbase = (wn * 32 + lr) * 64 + (lk ^ (lr & 7)) * 8;
  short8 afr[2][2], gfr[2][2], ufr[2][2];

  for (int t = 0; t < nt; ++t) {
    const int s = t & 1;
    const u16* LA = lds + (size_t)(s * 2) * 16384;
    const u16* LB = lds + (size_t)(s * 2 + 1) * 16384;
    PHASE_GU(0, if (t + 1 < nt) STAGE8(s ^ 1, 0, 0, t + 1), ((void)0));
    PHASE_GU(1, if (t + 1 < nt) STAGE8(s ^ 1, 0, 1, t + 1), ((void)0));
    PHASE_GU(2, if (t + 2 < nt) STAGE8(s, 1, 0, t + 2), ((void)0));
    PHASE_GU(3, if (t + 2 < nt) STAGE8(s, 1, 1, t + 2),
             if (t + 2 < nt) { asm volatile("s_waitcnt vmcnt(4)" ::: "memory"); }
             else            { asm volatile("s_waitcnt vmcnt(0)" ::: "memory"); });
    __builtin_amdgcn_sched_barrier(0);
  }

#pragma unroll
  for (int m = 0; m < 8; ++m)
#pragma unroll
    for (int i = 0; i < 4; ++i) {
      int slot = bm0 + wm * 128 + m * 16 + lk * 4 + i;
      float w = wlist[e * T_TOK + slot];
#pragma unroll
      for (int n = 0; n < 2; ++n) {
        int col = bn0 + wn * 32 + n * 16 + lr;
        float g = accg[m][n][i], u = accu[m][n][i];
        float act = w * (g / (1.f + expf(-g))) * u;
        actC[((size_t)e * SLOTMAX + slot) * F_DIM + col] = f2bf(act);
      }
    }
}

// ---------------- per-expert down: outE[e][slot][h] = actC_e @ Wd_e^T (bf16) ------------
#define PHASE_D(p_, STAGE_STMT, WAIT_STMT)                                        \
  {                                                                               \
    afr[0][0] = *(const short8*)(LA + (abase + (2*(p_)) * 1024));                 \
    afr[0][1] = *(const short8*)(LA + ((abase + (2*(p_)) * 1024) ^ 32));          \
    afr[1][0] = *(const short8*)(LA + (abase + (2*(p_)+1) * 1024));               \
    afr[1][1] = *(const short8*)(LA + ((abase + (2*(p_)+1) * 1024) ^ 32));        \
    if ((p_) == 0) {                                                              \
      _Pragma("unroll") for (int n = 0; n < 4; ++n) {                             \
        bfr[n][0] = *(const short8*)(LB + (bbase + n * 1024));                    \
        bfr[n][1] = *(const short8*)(LB + ((bbase + n * 1024) ^ 32));             \
      }                                                                           \
    }                                                                             \
    STAGE_STMT; WAIT_STMT;                                                        \
    __builtin_amdgcn_s_barrier();                                                 \
    __builtin_amdgcn_s_setprio(1);                                                \
    _Pragma("unroll") for (int n = 0; n < 4; ++n) {                               \
      acc[2*(p_)][n]   = __builtin_amdgcn_mfma_f32_16x16x32_bf16(afr[0][0], bfr[n][0], acc[2*(p_)][n],   0,0,0); \
      acc[2*(p_)][n]   = __builtin_amdgcn_mfma_f32_16x16x32_bf16(afr[0][1], bfr[n][1], acc[2*(p_)][n],   0,0,0); \
      acc[2*(p_)+1][n] = __builtin_amdgcn_mfma_f32_16x16x32_bf16(afr[1][0], bfr[n][0], acc[2*(p_)+1][n], 0,0,0); \
      acc[2*(p_)+1][n] = __builtin_amdgcn_mfma_f32_16x16x32_bf16(afr[1][1], bfr[n][1], acc[2*(p_)+1][n], 0,0,0); \
    }                                                                             \
    __builtin_amdgcn_s_setprio(0);                                                \
    __builtin_amdgcn_s_barrier();                                                 \
  }

__global__ __launch_bounds__(512, 2)
void k8d(const u16* __restrict__ actC, const u16* __restrict__ Wd,
         const int* __restrict__ counts, u16* __restrict__ outE)
{
  extern __shared__ u16 lds[];
  const int tid = threadIdx.x;
  const int wid = tid >> 6, lane = tid & 63;
  const int wm = wid >> 2, wn = wid & 3;       // wave tile: 128 slots x 64 h
  const int lr = lane & 15, lk = lane >> 4;
  const int e = blockIdx.z;
  if ((int)blockIdx.y * 256 >= counts[e]) return;
  const int bm0 = blockIdx.y * 256;
  const int bn0 = blockIdx.x * 256;
  const int nt = F_DIM / 64;

  const int rl  = tid >> 3;
  const int csw = ((tid & 7) ^ (rl & 7)) * 8;
  const u16* srcp[2][2][2];
#pragma unroll
  for (int h = 0; h < 2; ++h)
#pragma unroll
    for (int c = 0; c < 2; ++c) {
      srcp[0][h][c] = actC + ((size_t)e * SLOTMAX + bm0 + h * 128 + c * 64 + rl) * F_DIM + csw;
      srcp[1][h][c] = Wd + (size_t)e * H_DIM * F_DIM
                    + (size_t)(bn0 + h * 128 + c * 64 + rl) * F_DIM + csw;
    }

  f32x4 acc[8][4];
  f32x4 zero4 = {0.f, 0.f, 0.f, 0.f};
#pragma unroll
  for (int m = 0; m < 8; ++m)
#pragma unroll
    for (int n = 0; n < 4; ++n) acc[m][n] = zero4;

  STAGE8(0, 0, 0, 0); STAGE8(0, 0, 1, 0); STAGE8(0, 1, 0, 0); STAGE8(0, 1, 1, 0);
  STAGE8(1, 1, 0, 1); STAGE8(1, 1, 1, 1);
  asm volatile("s_waitcnt vmcnt(4)" ::: "memory");
  __builtin_amdgcn_s_barrier();

  const int abase = (wm * 128 + lr) * 64 + (lk ^ (lr & 7)) * 8;
  const int bbase = (wn * 64 + lr) * 64 + (lk ^ (lr & 7)) * 8;
  short8 afr[2][2], bfr[4][2];

  for (int t = 0; t < nt; ++t) {
    const int s = t & 1;
    const u16* LA = lds + (size_t)(s * 2) * 16384;
    const u16* LB = lds + (size_t)(s * 2 + 1) * 16384;
    PHASE_D(0, if (t + 1 < nt) STAGE8(s ^ 1, 0, 0, t + 1), ((void)0));
    PHASE_D(1, if (t + 1 < nt) STAGE8(s ^ 1, 0, 1, t + 1), ((void)0));
    PHASE_D(2, if (t + 2 < nt) STAGE8(s, 1, 0, t + 2), ((void)0));
    PHASE_D(3, if (t + 2 < nt) STAGE8(s, 1, 1, t + 2),
            if (t + 2 < nt) { asm volatile("s_waitcnt vmcnt(4)" ::: "memory"); }
            else            { asm volatile("s_waitcnt vmcnt(0)" ::: "memory"); });
    __builtin_amdgcn_sched_barrier(0);
  }

#pragma unroll
  for (int m = 0; m < 8; ++m)
#pragma unroll
    for (int n = 0; n < 4; ++n)
#pragma unroll
      for (int i = 0; i < 4; ++i) {
        int slot = bm0 + wm * 128 + m * 16 + lk * 4 + i;
        int col  = bn0 + wn * 64 + n * 16 + lr;
        outE[((size_t)e * SLOTMAX + slot) * H_DIM + col] = f2bf(acc[m][n][i]);
      }
}

// ---------------- gather-reduce: y[t,h] = sum_{r<8} outE[tokmap[t][r]][h] ----------------
__global__ void k_gather(const u16* __restrict__ outE, const int* __restrict__ tokmap,
                         float* __restrict__ y)
{
  __shared__ int tm[8];
  const int t = blockIdx.x, tid = threadIdx.x;
  if (tid < 8) tm[tid] = tokmap[t * 8 + tid];
  __syncthreads();
  float s[8] = {0.f, 0.f, 0.f, 0.f, 0.f, 0.f, 0.f, 0.f};
#pragma unroll
  for (int r = 0; r < 8; ++r) {
    union { short8 v; u16 e[8]; } row;
    row.v = *(const short8*)(outE + (size_t)tm[r] * H_DIM + tid * 8);
#pragma unroll
    for (int j = 0; j < 8; ++j) s[j] += bf2f(row.e[j]);
  }
  float* dst = y + (size_t)t * H_DIM + tid * 8;
#pragma unroll
  for (int j = 0; j < 8; ++j) dst[j] = s[j];
}

// ---------------- small GEMM for h1: C = silu(A*B^T + bias) -> bf16 ----------------
__global__ __launch_bounds__(256, 2)
void k_gemm_h1(const u16* __restrict__ A, const u16* __restrict__ B, int Ndim, int Kdim,
               u16* __restrict__ Cb, const float* __restrict__ bias)
{
  __shared__ __align__(16) u16 As[128 * 32];
  __shared__ __align__(16) u16 Bs[64 * 32];
  const int tid = threadIdx.x;
  const int bm0 = blockIdx.y * 128;
  const int bn0 = blockIdx.x * 64;
  const int wid = tid >> 6, lane = tid & 63;
  const int lr = lane & 15, lk = lane >> 4;
  const int srow = tid >> 2, scol = (tid & 3) * 8;

  f32x4 zero4 = {0.f, 0.f, 0.f, 0.f};
  f32x4 acc[2][4];
#pragma unroll
  for (int m = 0; m < 2; ++m)
#pragma unroll
    for (int n = 0; n < 4; ++n) acc[m][n] = zero4;

  const u16* Ag = A + (size_t)(bm0 + srow) * Kdim + scol;
  const u16* Bg = B + (size_t)(bn0 + srow) * Kdim + scol;
  u16* AsP = As + srow * 32 + scol;
  u16* BsP = Bs + srow * 32 + scol;

  for (int k0 = 0; k0 < Kdim; k0 += 32) {
    gl_lds16(Ag + k0, AsP);
    gl_lds16(Ag + k0 + (size_t)64 * Kdim, AsP + 64 * 32);
    gl_lds16(Bg + k0, BsP);
    __syncthreads();
    short8 a[2], b[4];
#pragma unroll
    for (int m = 0; m < 2; ++m)
      a[m] = *(const short8*)(As + (wid * 32 + m * 16 + lr) * 32 + lk * 8);
#pragma unroll
    for (int n = 0; n < 4; ++n)
      b[n] = *(const short8*)(Bs + (n * 16 + lr) * 32 + lk * 8);
#pragma unroll
    for (int m = 0; m < 2; ++m)
#pragma unroll
      for (int n = 0; n < 4; ++n)
        acc[m][n] = __builtin_amdgcn_mfma_f32_16x16x32_bf16(a[m], b[n], acc[m][n], 0, 0, 0);
    __syncthreads();
  }

#pragma unroll
  for (int m = 0; m < 2; ++m)
#pragma unroll
    for (int n = 0; n < 4; ++n)
#pragma unroll
      for (int i = 0; i < 4; ++i) {
        int r = bm0 + wid * 32 + m * 16 + lk * 4 + i;
        int c = bn0 + n * 16 + lr;
        float v = acc[m][n][i] + bias[c];
        v = v / (1.f + expf(-v));
        Cb[(size_t)r * Ndim + c] = f2bf(v);
      }
}

// ---------------- fallback kernels (small-ws path) ----------------
__global__ __launch_bounds__(256, 2)
void k_down(const u16* __restrict__ A, const u16* __restrict__ B, float* __restrict__ C)
{
  __shared__ __align__(16) u16 As[128 * 32];
  __shared__ __align__(16) u16 Bs[128 * 32];
  const int bid = blockIdx.x;
  const int swz = (bid & 7) * 32 + (bid >> 3);
  const int bm0 = (swz >> 4) * 128;
  const int bn0 = (swz & 15) * 128;
  const int tid = threadIdx.x;
  const int wid = tid >> 6, lane = tid & 63;
  const int wr = (wid >> 1) * 64, wc = (wid & 1) * 64;
  const int lr = lane & 15, lk = lane >> 4;
  const int srow = tid >> 2, scol = (tid & 3) * 8;

  f32x4 zero4 = {0.f, 0.f, 0.f, 0.f};
  f32x4 acc[4][4];
#pragma unroll
  for (int m = 0; m < 4; ++m)
#pragma unroll
    for (int n = 0; n < 4; ++n) acc[m][n] = zero4;

  const u16* Ag = A + (size_t)(bm0 + srow) * EFD + scol;
  const u16* Bg = B + (size_t)(bn0 + srow) * EFD + scol;
  u16* AsP = As + srow * 32 + scol;
  u16* BsP = Bs + srow * 32 + scol;

  for (int k0 = 0; k0 < EFD; k0 += 32) {
    gl_lds16(Ag + k0, AsP);
    gl_lds16(Ag + k0 + (size_t)64 * EFD, AsP + 64 * 32);
    gl_lds16(Bg + k0, BsP);
    gl_lds16(Bg + k0 + (size_t)64 * EFD, BsP + 64 * 32);
    __syncthreads();
    short8 a[4], b[4];
#pragma unroll
    for (int m = 0; m < 4; ++m)
      a[m] = *(const short8*)(As + (wr + m * 16 + lr) * 32 + lk * 8);
#pragma unroll
    for (int n = 0; n < 4; ++n)
      b[n] = *(const short8*)(Bs + (wc + n * 16 + lr) * 32 + lk * 8);
#pragma unroll
    for (int m = 0; m < 4; ++m)
#pragma unroll
      for (int n = 0; n < 4; ++n)
        acc[m][n] = __builtin_amdgcn_mfma_f32_16x16x32_bf16(a[m], b[n], acc[m][n], 0, 0, 0);
    __syncthreads();
  }

#pragma unroll
  for (int m = 0; m < 4; ++m)
#pragma unroll
    for (int n = 0; n < 4; ++n)
#pragma unroll
      for (int i = 0; i < 4; ++i) {
        int r = bm0 + wr + m * 16 + lk * 4 + i;
        int c = bn0 + wc + n * 16 + lr;
        C[(size_t)r * H_DIM + c] = acc[m][n][i];
      }
}

__global__ __launch_bounds__(256, 2)
void k_gu_f32(const u16* __restrict__ Xbf, const float* __restrict__ Wg_, const float* __restrict__ Wu_,
              const int* __restrict__ list, const float* __restrict__ wlist,
              const int* __restrict__ counts, u16* __restrict__ actS)
{
  __shared__ __align__(16) u16 As[128 * 32];
  __shared__ __align__(16) u16 Gs[128 * 32];
  __shared__ __align__(16) u16 Us[128 * 32];
  const int e  = blockIdx.z;
  const int tb = blockIdx.y;
  if (tb * 128 >= counts[e]) return;
  const int f0 = blockIdx.x * 128;
  const int tid = threadIdx.x;
  const int wid = tid >> 6, lane = tid & 63;
  const int wr = (wid >> 1) * 64, wc = (wid & 1) * 64;
  const int lr = lane & 15, lk = lane >> 4;
  const int srow = tid >> 2, scol = (tid & 3) * 8;
  const int lbase = e * T_TOK + tb * 128;

  const int t0i = list[lbase + srow];
  const int t1i = list[lbase + 64 + srow];
  const u16* Ag0 = Xbf + (size_t)t0i * H_DIM + scol;
  const u16* Ag1 = Xbf + (size_t)t1i * H_DIM + scol;
  const size_t wrow = (size_t)(e * F_DIM + f0 + srow) * H_DIM + scol;

  f32x4 zero4 = {0.f, 0.f, 0.f, 0.f};
  f32x4 accg[4][4], accu[4][4];
#pragma unroll
  for (int m = 0; m < 4; ++m)
#pragma unroll
    for (int n = 0; n < 4; ++n) { accg[m][n] = zero4; accu[m][n] = zero4; }

  for (int k0 = 0; k0 < H_DIM; k0 += 32) {
    gl_lds16(Ag0 + k0, As + srow * 32 + scol);
    gl_lds16(Ag1 + k0, As + (64 + srow) * 32 + scol);
#pragma unroll
    for (int half = 0; half < 2; ++half) {
      size_t off = wrow + (size_t)(half * 64) * H_DIM + k0;
      float4 g0 = *(const float4*)(Wg_ + off), g1 = *(const float4*)(Wg_ + off + 4);
      float4 u0 = *(const float4*)(Wu_ + off), u1 = *(const float4*)(Wu_ + off + 4);
      union { short8 v; u16 ee[8]; } og, ou;
      og.ee[0] = f2bf(g0.x); og.ee[1] = f2bf(g0.y); og.ee[2] = f2bf(g0.z); og.ee[3] = f2bf(g0.w);
      og.ee[4] = f2bf(g1.x); og.ee[5] = f2bf(g1.y); og.ee[6] = f2bf(g1.z); og.ee[7] = f2bf(g1.w);
      ou.ee[0] = f2bf(u0.x); ou.ee[1] = f2bf(u0.y); ou.ee[2] = f2bf(u0.z); ou.ee[3] = f2bf(u0.w);
      ou.ee[4] = f2bf(u1.x); ou.ee[5] = f2bf(u1.y); ou.ee[6] = f2bf(u1.z); ou.ee[7] = f2bf(u1.w);
      *(short8*)(Gs + (half * 64 + srow) * 32 + scol) = og.v;
      *(short8*)(Us + (half * 64 + srow) * 32 + scol) = ou.v;
    }
    __syncthreads();
    short8 a[4], bg[4], bu[4];
#pragma unroll
    for (int m = 0; m < 4; ++m)
      a[m] = *(const short8*)(As + (wr + m * 16 + lr) * 32 + lk * 8);
#pragma unroll
    for (int n = 0; n < 4; ++n) {
      bg[n] = *(const short8*)(Gs + (wc + n * 16 + lr) * 32 + lk * 8);
      bu[n] = *(const short8*)(Us + (wc + n * 16 + lr) * 32 + lk * 8);
    }
#pragma unroll
    for (int m = 0; m < 4; ++m)
#pragma unroll
      for (int n = 0; n < 4; ++n) {
        accg[m][n] = __builtin_amdgcn_mfma_f32_16x16x32_bf16(a[m], bg[n], accg[m][n], 0, 0, 0);
        accu[m][n] = __builtin_amdgcn_mfma_f32_16x16x32_bf16(a[m], bu[n], accu[m][n], 0, 0, 0);
      }
    __syncthreads();
  }

#pragma unroll
  for (int m = 0; m < 4; ++m)
#pragma unroll
    for (int i = 0; i < 4; ++i) {
      int slot = tb * 128 + wr + m * 16 + lk * 4 + i;
      float w = wlist[e * T_TOK + slot];
      if (w > 0.f) {
        int t = list[e * T_TOK + slot];
        u16* dst = actS + (size_t)t * EFD + e * F_DIM + f0 + wc;
#pragma unroll
        for (int n = 0; n < 4; ++n) {
          float g = accg[m][n][i], u = accu[m][n][i];
          float act = w * (g / (1.f + expf(-g))) * u;
          dst[n * 16 + lr] = f2bf(act);
        }
      }
    }
}

// ---------------- per-token router (+ expert bitmask out) ----------------
__global__ void k_router(const float* __restrict__ x, const float* __restrict__ gu,
                         const u16* __restrict__ h1, const float* __restrict__ W2,
                         const float* __restrict__ b2, const float* __restrict__ gw,
                         const float* __restrict__ Umat, const float* __restrict__ alpha_p,
                         float* __restrict__ comb, unsigned* __restrict__ emask)
{
  __shared__ float xs[H_DIM];
  __shared__ float zbuf[8];
  __shared__ float rl[16];
  __shared__ int zi_s;
  const int t = blockIdx.x, tid = threadIdx.x;

  for (int i = tid; i < H_DIM / 4; i += 256)
    ((float4*)xs)[i] = ((const float4*)(x + (size_t)t * H_DIM))[i];

  int zg = tid >> 5, l32 = tid & 31;
  float zp = 0.f;
  const u16* h1r = h1 + (size_t)t * M_DIM;
  for (int j = l32; j < M_DIM; j += 32)
    zp += bf2f(h1r[j]) * W2[zg * M_DIM + j];
#pragma unroll
  for (int off = 16; off; off >>= 1) zp += __shfl_xor(zp, off);
  if (l32 == 0) zbuf[zg] = zp + b2[zg];
  __syncthreads();
  if (tid == 0) {
    float best = -1e30f; int bi = 0;
#pragma unroll
    for (int z = 0; z < 8; ++z) {
      float u = gu[t * 8 + z];
      float g = -logf(-logf(u + 1e-10f) + 1e-10f);
      float v = zbuf[z] + g;
      if (v > best) { best = v; bi = z; }
    }
    zi_s = bi;
  }
  __syncthreads();
  int eg = tid >> 4, l16 = tid & 15;
  float rp = 0.f;
  const float* gwr = gw + (size_t)eg * H_DIM;
  for (int j = l16; j < H_DIM; j += 16) rp += xs[j] * gwr[j];
#pragma unroll
  for (int off = 8; off; off >>= 1) rp += __shfl_xor(rp, off);
  if (l16 == 0) rl[eg] = rp;
  __syncthreads();
  if (tid == 0) {
    float a = alpha_p[0]; int zi = zi_s;
    float w[16], mx = -1e30f;
#pragma unroll
    for (int ee = 0; ee < 16; ++ee) { w[ee] = rl[ee] + a * Umat[zi * 16 + ee]; mx = fmaxf(mx, w[ee]); }
    float s = 0.f;
#pragma unroll
    for (int ee = 0; ee < 16; ++ee) { w[ee] = expf(w[ee] - mx); s += w[ee]; }
    float inv = 1.f / s;
    unsigned chosen = 0;
#pragma unroll
    for (int k = 0; k < 8; ++k) {
      float bw = -1.f; int bi = 0;
      for (int ee = 0; ee < 16; ++ee)
        if (!((chosen >> ee) & 1u) && w[ee] > bw) { bw = w[ee]; bi = ee; }
      chosen |= 1u << bi;
    }
    for (int ee = 0; ee < 16; ++ee)
      comb[t * 16 + ee] = ((chosen >> ee) & 1u) ? w[ee] * inv : 0.f;
    emask[t] = chosen;
  }
}

// ---------------- compaction (pad to 256) + tokmap fused ----------------
__global__ void k_compact(const float* __restrict__ comb, const unsigned* __restrict__ emask,
                          int* __restrict__ list, float* __restrict__ wlist,
                          int* __restrict__ counts, int* __restrict__ tokmap)
{
  __shared__ int sc[256];
  const int e = blockIdx.x, tid = threadIdx.x;
  int toks[8]; float ws[8]; int cnt = 0;
#pragma unroll
  for (int i = 0; i < 8; ++i) {
    int t = tid * 8 + i;
    float w = comb[t * E_NUM + e];
    if (w > 0.f) { toks[cnt] = t; ws[cnt] = w; ++cnt; }
  }
  sc[tid] = cnt;
  __syncthreads();
  for (int off = 1; off < 256; off <<= 1) {
    int v = (tid >= off) ? sc[tid - off] : 0;
    __syncthreads();
    sc[tid] += v;
    __syncthreads();
  }
  int base = sc[tid] - cnt;
  int total = sc[255];
  int padded = (total + 255) & ~255;
  int* lp = list + e * T_TOK;
  float* wp = wlist + e * T_TOK;
  for (int j = 0; j < cnt; ++j) {
    int t = toks[j];
    lp[base + j] = t; wp[base + j] = ws[j];
    int r = __popc(emask[t] & ((1u << e) - 1u));
    tokmap[t * 8 + r] = e * SLOTMAX + base + j;
  }
  for (int j = total + tid; j < padded; j += 256) { lp[j] = 0; wp[j] = 0.f; }
  if (tid == 0) counts[e] = padded;
}

extern "C" void kernel_launch(void* const* d_in, const int* in_sizes, int n_in,
                              void* d_out, int out_size, void* d_ws, size_t ws_size,
                              hipStream_t stream)
{
  const float* x  = (const float*)d_in[0];
  const float* gu = (const float*)d_in[1];
  const float* W1 = (const float*)d_in[2];
  const float* b1 = (const float*)d_in[3];
  const float* W2 = (const float*)d_in[4];
  const float* b2 = (const float*)d_in[5];
  const float* gw = (const float*)d_in[6];
  const float* Um = (const float*)d_in[7];
  const float* al = (const float*)d_in[8];
  const float* Wg = (const float*)d_in[9];
  const float* Wu = (const float*)d_in[10];
  const float* Wd = (const float*)d_in[11];
  float* y = (float*)d_out;

  size_t off = 0;
  char* base = (char*)d_ws;
  auto take = [&](size_t b) { char* p = base + off; off += (b + 255) & ~(size_t)255; return p; };
  u16*      x_bf   = (u16*)take((size_t)T_TOK * H_DIM * 2);
  u16*      W1_bf  = (u16*)take((size_t)M_DIM * H_DIM * 2);
  u16*      h1_bf  = (u16*)take((size_t)T_TOK * M_DIM * 2);
  float*    comb   = (float*)take((size_t)T_TOK * E_NUM * 4);
  int*      list   = (int*)take((size_t)E_NUM * T_TOK * 4);
  float*    wlist  = (float*)take((size_t)E_NUM * T_TOK * 4);
  int*      counts = (int*)take(64 * 4);
  unsigned* emask  = (unsigned*)take((size_t)T_TOK * 4);
  int*      tokmap = (int*)take((size_t)T_TOK * 8 * 4);
  u16*      actC   = (u16*)take((size_t)E_NUM * SLOTMAX * F_DIM * 2);   // 67MB (fb: dense actS)
  u16*      outE   = (u16*)take((size_t)E_NUM * SLOTMAX * H_DIM * 2);   // 134MB (fb: Wdp uses 67)
  u16*      Wg_bf  = (u16*)take((size_t)E_NUM * F_DIM * H_DIM * 2);
  u16*      Wu_bf  = (u16*)take((size_t)E_NUM * F_DIM * H_DIM * 2);
  u16*      Wd_bf  = (u16*)take((size_t)E_NUM * H_DIM * F_DIM * 2);
  bool big = (off <= ws_size);

  if (big) {
    // one dispatch: x, W1, Wg, Wu -> bf16 (Wd deferred until after k8gu for L3 freshness)
    k_cvt_all<<<dim3(35328), 256, 0, stream>>>(x, W1, Wg, Wu, x_bf, W1_bf, Wg_bf, Wu_bf);
  } else {
    k_cvt<<<dim3((T_TOK * H_DIM / 8) / 256), 256, 0, stream>>>(x, x_bf, T_TOK * H_DIM / 8);
    k_cvt<<<dim3((M_DIM * H_DIM / 8) / 256), 256, 0, stream>>>(W1, W1_bf, M_DIM * H_DIM / 8);
  }

  k_gemm_h1<<<dim3(M_DIM / 64, T_TOK / 128), 256, 0, stream>>>(x_bf, W1_bf, M_DIM, H_DIM,
                                                               h1_bf, b1);
  k_router<<<dim3(T_TOK), 256, 0, stream>>>(x, gu, h1_bf, W2, b2, gw, Um, al, comb, emask);
  k_compact<<<dim3(E_NUM), 256, 0, stream>>>(comb, emask, list, wlist, counts, tokmap);

  if (big) {
    // fused gate+up -> compacted actC (Wg_bf/Wu_bf L3-warm from k_cvt_all)
    k8gu<<<dim3(F_DIM / 128, SLOTMAX / 256, E_NUM), 512, 131072, stream>>>(
        x_bf, Wg_bf, Wu_bf, list, wlist, counts, actC);
    // convert Wd now -> L3-warm for k8d
    k_cvt<<<dim3(16384), 256, 0, stream>>>(Wd, Wd_bf, E_NUM * H_DIM * F_DIM / 8);
    // per-expert down -> outE
    k8d<<<dim3(H_DIM / 256, SLOTMAX / 256, E_NUM), 512, 131072, stream>>>(
        actC, Wd_bf, counts, outE);
    k_gather<<<dim3(T_TOK), 256, 0, stream>>>(outE, tokmap, y);
  } else {
    u16* actS = actC;
    u16* Wdp  = outE;
    k_cvt_wd<<<dim3(16384), 256, 0, stream>>>(Wd, Wdp);
    (void)hipMemsetAsync(actS, 0, (size_t)T_TOK * EFD * 2, stream);
    k_gu_f32<<<dim3(F_DIM / 128, 16, E_NUM), 256, 0, stream>>>(x_bf, Wg, Wu,
                                                               list, wlist, counts, actS);
    k_down<<<dim3(256), 256, 0, stream>>>(actS, Wdp, y);
  }
}